// Round 1
// baseline (13729.385 us; speedup 1.0000x reference)
//
#include <hip/hip_runtime.h>
#include <math.h>

#define HD   512
#define G4H  2048
#define BB   256
#define UU   16
#define TTT  16
#define VVV  512
#define MDEC 4096   // B*U

__device__ __forceinline__ float sigmoidf_(float x) { return 1.f / (1.f + expf(-x)); }

// ---------------- transpose: WT[k][n] = W[n][col0+k], W is N x (ldw) ----------------
__global__ void transpose_w(const float* __restrict__ W, float* __restrict__ WT,
                            int N, int K, int ldw, int col0)
{
    __shared__ float tile[32][33];
    int kb = blockIdx.x * 32, nb = blockIdx.y * 32;
    int tx = threadIdx.x, ty = threadIdx.y;
    for (int i = ty; i < 32; i += 8)
        tile[i][tx] = W[(size_t)(nb + i) * ldw + col0 + kb + tx];
    __syncthreads();
    for (int i = ty; i < 32; i += 8)
        WT[(size_t)(kb + i) * N + nb + tx] = tile[tx][i];
}

// ---------------- GEMM, K fixed = 512, up to two (A,B) pairs accumulated ----------------
// C[m][n] = act( sum_p sum_k Ap[m][k] * Bp[k][n] + bias[n] )
// block 256 threads: 16 m-rows x 256 n-cols (each thread 4m x 4n)
__global__ __launch_bounds__(256) void gemm512(
    const float* __restrict__ A1, int lda1, const float* __restrict__ B1,
    const float* __restrict__ A2, int lda2, const float* __restrict__ B2,
    const float* __restrict__ bias, int act,
    float* __restrict__ C, int N)
{
    __shared__ float As[16][512];
    const int tid = threadIdx.x;
    const int nt = tid & 63, mt = tid >> 6;
    const int n  = blockIdx.x * 256 + nt * 4;
    const int m0 = blockIdx.y * 16;
    float acc[4][4] = {};

    for (int pair = 0; pair < 2; ++pair) {
        const float* A  = pair ? A2 : A1;
        const float* B  = pair ? B2 : B1;
        const int   lda = pair ? lda2 : lda1;
        if (A == nullptr) continue;           // uniform branch
        __syncthreads();
        for (int i = tid; i < 16 * 128; i += 256) {
            int mm = i >> 7, kq = (i & 127) << 2;
            *(float4*)(&As[mm][kq]) = *(const float4*)(&A[(size_t)(m0 + mm) * lda + kq]);
        }
        __syncthreads();
        #pragma unroll 4
        for (int k0 = 0; k0 < 512; k0 += 4) {
            float4 w0 = *(const float4*)(&B[(size_t)(k0 + 0) * N + n]);
            float4 w1 = *(const float4*)(&B[(size_t)(k0 + 1) * N + n]);
            float4 w2 = *(const float4*)(&B[(size_t)(k0 + 2) * N + n]);
            float4 w3 = *(const float4*)(&B[(size_t)(k0 + 3) * N + n]);
            #pragma unroll
            for (int i = 0; i < 4; ++i) {
                float4 a = *(const float4*)(&As[mt * 4 + i][k0]);
                acc[i][0] += a.x * w0.x + a.y * w1.x + a.z * w2.x + a.w * w3.x;
                acc[i][1] += a.x * w0.y + a.y * w1.y + a.z * w2.y + a.w * w3.y;
                acc[i][2] += a.x * w0.z + a.y * w1.z + a.z * w2.z + a.w * w3.z;
                acc[i][3] += a.x * w0.w + a.y * w1.w + a.z * w2.w + a.w * w3.w;
            }
        }
    }

    float bx = 0.f, by = 0.f, bz = 0.f, bw = 0.f;
    if (bias) { float4 bv = *(const float4*)(&bias[n]); bx = bv.x; by = bv.y; bz = bv.z; bw = bv.w; }
    #pragma unroll
    for (int i = 0; i < 4; ++i) {
        float4 r;
        r.x = acc[i][0] + bx; r.y = acc[i][1] + by; r.z = acc[i][2] + bz; r.w = acc[i][3] + bw;
        if (act) { r.x = tanhf(r.x); r.y = tanhf(r.y); r.z = tanhf(r.z); r.w = tanhf(r.w); }
        *(float4*)(&C[(size_t)(m0 + mt * 4 + i) * N + n]) = r;
    }
}

// ---------------- LSTM gate: consumes G (M x 2048) + optional adds, updates c,h ----------------
__global__ void lstm_gate(const float* __restrict__ G,
                          const float* __restrict__ addf,   // M x 2048 or null
                          const float* __restrict__ gtab,   // V x 2048 or null
                          const int*   __restrict__ gidx,   // stride gstride, or null
                          int gstride,
                          const float* __restrict__ ba, const float* __restrict__ bb,
                          float* __restrict__ c_state,
                          float* __restrict__ h_out,
                          float* __restrict__ h_copy, int h_copy_ld,
                          int M)
{
    int idx = blockIdx.x * 256 + threadIdx.x;
    if (idx >= M * HD) return;
    int m = idx >> 9, u = idx & 511;
    const float* g = G + (size_t)m * G4H;
    float gi = g[u], gf = g[u + 512], gg = g[u + 1024], go = g[u + 1536];
    if (addf) {
        const float* a = addf + (size_t)m * G4H;
        gi += a[u]; gf += a[u + 512]; gg += a[u + 1024]; go += a[u + 1536];
    }
    if (gtab) {
        int id = gidx[(size_t)m * gstride];
        const float* a = gtab + (size_t)id * G4H;
        gi += a[u]; gf += a[u + 512]; gg += a[u + 1024]; go += a[u + 1536];
    }
    if (ba) { gi += ba[u]; gf += ba[u + 512]; gg += ba[u + 1024]; go += ba[u + 1536]; }
    if (bb) { gi += bb[u]; gf += bb[u + 512]; gg += bb[u + 1024]; go += bb[u + 1536]; }
    float c = sigmoidf_(gf) * c_state[idx] + sigmoidf_(gi) * tanhf(gg);
    c_state[idx] = c;
    float h = sigmoidf_(go) * tanhf(c);
    h_out[idx] = h;
    if (h_copy) h_copy[(size_t)m * h_copy_ld + u] = h;
}

// ---------------- splits ----------------
__global__ void split_ci(const float* __restrict__ ci, float* __restrict__ h1,
                         float* __restrict__ h2, float* __restrict__ c1, float* __restrict__ c2)
{
    int idx = blockIdx.x * 256 + threadIdx.x;  // B*H
    int b = idx >> 9, u = idx & 511;
    const float* r = ci + (size_t)b * G4H;
    h1[idx] = r[u]; h2[idx] = r[u + 512]; c1[idx] = r[u + 1024]; c2[idx] = r[u + 1536];
}

__global__ void split_states(const float* __restrict__ st, float* __restrict__ h0,
                             float* __restrict__ h1d, float* __restrict__ c0,
                             float* __restrict__ c1d, float* __restrict__ hinit)
{
    int idx = blockIdx.x * 256 + threadIdx.x;  // MDEC*H
    int m = idx >> 9, u = idx & 511;
    const float* r = st + (size_t)m * G4H;
    float a = r[u], b = r[u + 512];
    h0[idx] = a; h1d[idx] = b; c0[idx] = r[u + 1024]; c1d[idx] = r[u + 1536];
    hinit[idx] = a + b;
}

// ---------------- bias + softmax over V=512, write into out ----------------
__global__ void softmax_out(const float* __restrict__ L, const float* __restrict__ bo,
                            float* __restrict__ out, int t)
{
    int m = blockIdx.x, tid = threadIdx.x;
    float x0 = L[(size_t)m * VVV + tid]       + bo[tid];
    float x1 = L[(size_t)m * VVV + tid + 256] + bo[tid + 256];
    float mx = fmaxf(x0, x1);
    #pragma unroll
    for (int off = 32; off; off >>= 1) mx = fmaxf(mx, __shfl_xor(mx, off));
    __shared__ float sm[4], ss[4];
    if ((tid & 63) == 0) sm[tid >> 6] = mx;
    __syncthreads();
    mx = fmaxf(fmaxf(sm[0], sm[1]), fmaxf(sm[2], sm[3]));
    float e0 = expf(x0 - mx), e1 = expf(x1 - mx);
    float s = e0 + e1;
    #pragma unroll
    for (int off = 32; off; off >>= 1) s += __shfl_xor(s, off);
    if ((tid & 63) == 0) ss[tid >> 6] = s;
    __syncthreads();
    s = ss[0] + ss[1] + ss[2] + ss[3];
    float inv = 1.f / s;
    float* o = out + ((size_t)m * TTT + t) * VVV;
    o[tid] = e0 * inv;
    o[tid + 256] = e1 * inv;
}

// ---------------- host ----------------
extern "C" void kernel_launch(void* const* d_in, const int* in_sizes, int n_in,
                              void* d_out, int out_size, void* d_ws, size_t ws_size,
                              hipStream_t stream)
{
    const float* z     = (const float*)d_in[0];
    const int*   x     = (const int*)  d_in[1];
    const float* Wc    = (const float*)d_in[2];
    const float* bc    = (const float*)d_in[3];
    const float* cWih0 = (const float*)d_in[4];
    const float* cWhh0 = (const float*)d_in[5];
    const float* cbih0 = (const float*)d_in[6];
    const float* cbhh0 = (const float*)d_in[7];
    const float* cWih1 = (const float*)d_in[8];
    const float* cWhh1 = (const float*)d_in[9];
    const float* cbih1 = (const float*)d_in[10];
    const float* cbhh1 = (const float*)d_in[11];
    const float* Wd    = (const float*)d_in[12];
    const float* bd    = (const float*)d_in[13];
    const float* dWih0 = (const float*)d_in[14];
    const float* dWhh0 = (const float*)d_in[15];
    const float* dbih0 = (const float*)d_in[16];
    const float* dbhh0 = (const float*)d_in[17];
    const float* dWih1 = (const float*)d_in[18];
    const float* dWhh1 = (const float*)d_in[19];
    const float* dbih1 = (const float*)d_in[20];
    const float* dbhh1 = (const float*)d_in[21];
    const float* emb   = (const float*)d_in[22];
    const float* Wo    = (const float*)d_in[23];
    const float* bo    = (const float*)d_in[24];
    float* out = (float*)d_out;

    float* ws = (float*)d_ws;
    size_t off = 0;
    auto alloc = [&](size_t n) { float* p = ws + off; off += n; return p; };
    float* WcT    = alloc(512 * 2048);
    float* cWih0T = alloc(512 * 2048);
    float* cWhh0T = alloc(512 * 2048);
    float* cWih1T = alloc(512 * 2048);
    float* cWhh1T = alloc(512 * 2048);
    float* WdT    = alloc(512 * 2048);
    float* dW1T   = alloc(512 * 2048);   // dWih0[:, :512]^T  (embedding half)
    float* dW2T   = alloc(512 * 2048);   // dWih0[:, 512:]^T  (h_init half)
    float* dWhh0T = alloc(512 * 2048);
    float* dWih1T = alloc(512 * 2048);
    float* dWhh1T = alloc(512 * 2048);
    float* WoT    = alloc(512 * 512);
    float* embW0  = alloc(512 * 2048);   // emb @ dW1T  (V x 4H)
    float* ci     = alloc(BB * G4H);
    float* h1     = alloc(BB * HD);
    float* c1     = alloc(BB * HD);
    float* h2     = alloc(BB * HD);
    float* c2     = alloc(BB * HD);
    float* cond   = alloc((size_t)MDEC * HD);   // rows m = b*U + u
    float* Gbuf   = alloc((size_t)MDEC * G4H);
    float* hinitg = alloc((size_t)MDEC * G4H);
    float* h0     = alloc((size_t)MDEC * HD);
    float* c0     = alloc((size_t)MDEC * HD);
    float* h1d    = alloc((size_t)MDEC * HD);
    float* c1d    = alloc((size_t)MDEC * HD);
    float* hinit  = alloc((size_t)MDEC * HD);
    (void)ws_size; (void)in_sizes; (void)n_in; (void)out_size;

    dim3 tb(32, 8);
    auto TR = [&](const float* W, float* WT, int N, int K, int ldw, int col0) {
        dim3 g(K / 32, N / 32);
        transpose_w<<<g, tb, 0, stream>>>(W, WT, N, K, ldw, col0);
    };
    TR(Wc,    WcT,    2048, 512, 512,  0);
    TR(cWih0, cWih0T, 2048, 512, 512,  0);
    TR(cWhh0, cWhh0T, 2048, 512, 512,  0);
    TR(cWih1, cWih1T, 2048, 512, 512,  0);
    TR(cWhh1, cWhh1T, 2048, 512, 512,  0);
    TR(Wd,    WdT,    2048, 512, 512,  0);
    TR(dWih0, dW1T,   2048, 512, 1024, 0);
    TR(dWih0, dW2T,   2048, 512, 1024, 512);
    TR(dWhh0, dWhh0T, 2048, 512, 512,  0);
    TR(dWih1, dWih1T, 2048, 512, 512,  0);
    TR(dWhh1, dWhh1T, 2048, 512, 512,  0);
    TR(Wo,    WoT,    512,  512, 512,  0);

    auto GEMM = [&](const float* A1, int lda1, const float* B1,
                    const float* A2, int lda2, const float* B2,
                    const float* bias, int act, float* C, int M, int N) {
        dim3 g(N / 256, M / 16);
        gemm512<<<g, dim3(256), 0, stream>>>(A1, lda1, B1, A2, lda2, B2, bias, act, C, N);
    };
    auto GATE = [&](const float* G, const float* addf, const float* gtab,
                    const int* gidx, int gstride, const float* ba, const float* bb,
                    float* c_state, float* h_out, float* h_copy, int h_copy_ld, int M) {
        lstm_gate<<<dim3((M * HD) / 256), dim3(256), 0, stream>>>(
            G, addf, gtab, gidx, gstride, ba, bb, c_state, h_out, h_copy, h_copy_ld, M);
    };

    // Phase A: ci = tanh(z @ Wc.T + bc); split into h1,h2,c1,c2
    GEMM(z, 512, WcT, nullptr, 0, nullptr, bc, 1, ci, BB, G4H);
    split_ci<<<dim3(BB * HD / 256), dim3(256), 0, stream>>>(ci, h1, h2, c1, c2);

    // embW0 = emb @ dWih0[:, :512].T  (token -> input-gate table)
    GEMM(emb, 512, dW1T, nullptr, 0, nullptr, nullptr, 0, embW0, VVV, G4H);

    // Phase B: conditioning LSTM, 16 steps x 2 cells (o starts at zero)
    for (int u = 0; u < UU; ++u) {
        // cell 1: g = o @ cWih0.T + h1 @ cWhh0.T  (o = h2 from prev step; zero at u=0)
        GEMM(u > 0 ? h2 : nullptr, 512, cWih0T, h1, 512, cWhh0T, nullptr, 0, Gbuf, BB, G4H);
        GATE(Gbuf, nullptr, nullptr, nullptr, 0, cbih0, cbhh0, c1, h1, nullptr, 0, BB);
        // cell 2: g = h1_new @ cWih1.T + h2 @ cWhh1.T ; h2 also written to cond rows (b*U+u)
        GEMM(h1, 512, cWih1T, h2, 512, cWhh1T, nullptr, 0, Gbuf, BB, G4H);
        GATE(Gbuf, nullptr, nullptr, nullptr, 0, cbih1, cbhh1, c2, h2, cond + (size_t)u * HD, UU * HD, BB);
    }

    // Phase C: states = tanh(cond @ Wd.T + bd) -> split to decoder init states + h_init
    GEMM(cond, 512, WdT, nullptr, 0, nullptr, bd, 1, Gbuf, MDEC, G4H);
    split_states<<<dim3((size_t)MDEC * HD / 256), dim3(256), 0, stream>>>(Gbuf, h0, h1d, c0, c1d, hinit);

    // hinit_g = h_init @ dWih0[:, 512:].T  (dbih0 added in gate)
    GEMM(hinit, 512, dW2T, nullptr, 0, nullptr, nullptr, 0, hinitg, MDEC, G4H);

    // Phase D: decoder, 16 steps
    for (int t = 0; t < TTT; ++t) {
        // layer 0: g = embW0[x[:,t-1]] + hinit_g + h0 @ dWhh0.T + dbih0 + dbhh0
        GEMM(h0, 512, dWhh0T, nullptr, 0, nullptr, nullptr, 0, Gbuf, MDEC, G4H);
        GATE(Gbuf, hinitg, t > 0 ? embW0 : nullptr, t > 0 ? x + (t - 1) : nullptr, TTT,
             dbih0, dbhh0, c0, h0, nullptr, 0, MDEC);
        // layer 1: g = y0 @ dWih1.T + h1d @ dWhh1.T + dbih1 + dbhh1   (y0 == new h0)
        GEMM(h0, 512, dWih1T, h1d, 512, dWhh1T, nullptr, 0, Gbuf, MDEC, G4H);
        GATE(Gbuf, nullptr, nullptr, nullptr, 0, dbih1, dbhh1, c1d, h1d, nullptr, 0, MDEC);
        // logits + softmax -> out
        GEMM(h1d, 512, WoT, nullptr, 0, nullptr, nullptr, 0, Gbuf, MDEC, VVV);
        softmax_out<<<dim3(MDEC), dim3(256), 0, stream>>>(Gbuf, bo, out, t);
    }
}

// Round 2
// 5697.989 us; speedup vs baseline: 2.4095x; 2.4095x over previous
//
#include <hip/hip_runtime.h>
#include <math.h>

#define HD   512
#define G4H  2048
#define BB   256
#define UU   16
#define TTT  16
#define VVV  512
#define MDEC 4096   // B*U

#define AS1 __attribute__((address_space(1)))
#define AS3 __attribute__((address_space(3)))

typedef __attribute__((ext_vector_type(8))) short short8v;
typedef __attribute__((ext_vector_type(16))) float f32x16;

__device__ __forceinline__ float sigmoidf_(float x) { return 1.f / (1.f + expf(-x)); }

__device__ __forceinline__ unsigned short f2bf(float f) {
    unsigned int u = __float_as_uint(f);
    unsigned int r = (u + 0x7FFF + ((u >> 16) & 1)) >> 16;
    return (unsigned short)r;
}
__device__ __forceinline__ float bf2f(unsigned short s) {
    return __uint_as_float(((unsigned int)s) << 16);
}
__device__ __forceinline__ void split3(float v, short& h, short& m, short& l) {
    unsigned short hh = f2bf(v);
    float r1 = v - bf2f(hh);
    unsigned short mm = f2bf(r1);
    float r2 = r1 - bf2f(mm);
    unsigned short ll = f2bf(r2);
    h = (short)hh; m = (short)mm; l = (short)ll;
}

// fragment-ready offset for element (m,k), K=512 fixed:
// off = ((m>>5)*64 + (k>>3))*256 + (m&31)*8 + (k&7)
__device__ __forceinline__ size_t offf(int m, int k) {
    return ((size_t)((m >> 5) * 64 + (k >> 3))) * 256 + (size_t)((m & 31) * 8 + (k & 7));
}

// ---------------- transpose + 3-way split: W (N x ldw) -> blocked bf16 planes ----------------
__global__ void transpose_split(const float* __restrict__ Wsrc, short* __restrict__ pl, size_t ps,
                                int ldw, int col0, int total)
{
    int o = blockIdx.x * 256 + threadIdx.x;
    if (o >= total) return;
    int c = o >> 8, w = o & 255, r = w >> 3, j = w & 7;
    int n = (c >> 6) * 32 + r, k = (c & 63) * 8 + j;
    float v = Wsrc[(size_t)n * ldw + col0 + k];
    short h, m, l; split3(v, h, m, l);
    pl[o] = h; pl[ps + o] = m; pl[2 * ps + o] = l;
}

// ---------------- f32 row-major (M x 512) -> blocked bf16 planes ----------------
__global__ void convert_planes(const float* __restrict__ in, short* __restrict__ pl, size_t ps, int total)
{
    int o = blockIdx.x * 256 + threadIdx.x;
    if (o >= total) return;
    int c = o >> 8, w = o & 255, r = w >> 3, j = w & 7;
    int m = (c >> 6) * 32 + r, k = (c & 63) * 8 + j;
    float v = in[(size_t)m * 512 + k];
    short h, mm, l; split3(v, h, mm, l);
    pl[o] = h; pl[ps + o] = mm; pl[2 * ps + o] = l;
}

// ---------------- MFMA GEMM: C[MxN] = sum_pairs A_p (MxK=512, 3 planes) * B_p (512xN, 3 planes) ----------------
// 6-product bf16 triple-split. Block = 256 thr (4 waves, 2x2), tile 128x128, BK=16.
__global__ __launch_bounds__(256, 2) void mfma6_gemm(
    const short* __restrict__ A1, const short* __restrict__ B1,
    const short* __restrict__ A2, const short* __restrict__ B2,
    const float* __restrict__ bias, int act,
    float* __restrict__ C, int M, int N, int nsteps)
{
    __shared__ __align__(16) short lds[2][12288];   // 2 x 24KB: [A: 3 planes x 4 blk x 512][B: same]
    const int tid  = threadIdx.x;
    const int lane = tid & 63, wid = tid >> 6;
    const int wm = wid >> 1, wn = wid & 1;
    const int l31 = lane & 31, loct = lane >> 5;
    const int mblk0 = blockIdx.y * 4, nblk0 = blockIdx.x * 4;
    const size_t planeA = (size_t)M * 512, planeB = (size_t)N * 512;

    int ldo[6]; size_t goff[6]; int isB[6];
    #pragma unroll
    for (int i = 0; i < 6; ++i) {
        int c = wid + 4 * i;
        int s = (c >= 12) ? 1 : 0;
        int cc = c - 12 * s;
        int plane = cc >> 2, blk = cc & 3;
        ldo[i] = c * 512;
        isB[i] = s;
        goff[i] = (size_t)plane * (s ? planeB : planeA)
                + ((size_t)((s ? nblk0 : mblk0) + blk)) * 16384
                + (size_t)lane * 8;
    }
    const short* sp[6];
    #pragma unroll
    for (int i = 0; i < 6; ++i) sp[i] = (isB[i] ? B1 : A1) + goff[i];

    f32x16 acc[2][2] = {};

    // prologue stage into buf 0
    {
        short* db = &lds[0][0];
        #pragma unroll
        for (int i = 0; i < 6; ++i) {
            __builtin_amdgcn_global_load_lds((const AS1 unsigned int*)sp[i],
                                             (AS3 unsigned int*)(db + ldo[i]), 16, 0, 0);
            sp[i] += 512;
        }
    }
    __syncthreads();

    for (int t = 0; t < nsteps; ++t) {
        const int cur = t & 1;
        if (t + 1 < nsteps) {
            if (t + 1 == 32) {
                #pragma unroll
                for (int i = 0; i < 6; ++i) sp[i] = (isB[i] ? B2 : A2) + goff[i];
            }
            short* db = &lds[cur ^ 1][0];
            #pragma unroll
            for (int i = 0; i < 6; ++i) {
                __builtin_amdgcn_global_load_lds((const AS1 unsigned int*)sp[i],
                                                 (AS3 unsigned int*)(db + ldo[i]), 16, 0, 0);
                sp[i] += 512;
            }
        }
        const short* L = &lds[cur][0];
        const int fb = loct * 256 + l31 * 8;
        short8v a[2][3], bf[2][3];
        #pragma unroll
        for (int p = 0; p < 3; ++p) {
            a[0][p]  = *(const short8v*)(L + p * 2048 + (wm * 2 + 0) * 512 + fb);
            a[1][p]  = *(const short8v*)(L + p * 2048 + (wm * 2 + 1) * 512 + fb);
            bf[0][p] = *(const short8v*)(L + 6144 + p * 2048 + (wn * 2 + 0) * 512 + fb);
            bf[1][p] = *(const short8v*)(L + 6144 + p * 2048 + (wn * 2 + 1) * 512 + fb);
        }
        #define PROD(pa, pb) \
            acc[0][0] = __builtin_amdgcn_mfma_f32_32x32x16_bf16(a[0][pa], bf[0][pb], acc[0][0], 0, 0, 0); \
            acc[0][1] = __builtin_amdgcn_mfma_f32_32x32x16_bf16(a[0][pa], bf[1][pb], acc[0][1], 0, 0, 0); \
            acc[1][0] = __builtin_amdgcn_mfma_f32_32x32x16_bf16(a[1][pa], bf[0][pb], acc[1][0], 0, 0, 0); \
            acc[1][1] = __builtin_amdgcn_mfma_f32_32x32x16_bf16(a[1][pa], bf[1][pb], acc[1][1], 0, 0, 0);
        PROD(0, 0) PROD(0, 1) PROD(1, 0) PROD(1, 1) PROD(0, 2) PROD(2, 0)
        #undef PROD
        __syncthreads();
    }

    // epilogue: C/D layout col=lane&31, row=(reg&3)+8*(reg>>2)+4*(lane>>5)
    #pragma unroll
    for (int fm = 0; fm < 2; ++fm) {
        #pragma unroll
        for (int fn = 0; fn < 2; ++fn) {
            int col = blockIdx.x * 128 + wn * 64 + fn * 32 + l31;
            float bv = bias ? bias[col] : 0.f;
            int rbase = blockIdx.y * 128 + wm * 64 + fm * 32 + 4 * loct;
            #pragma unroll
            for (int reg = 0; reg < 16; ++reg) {
                int row = rbase + (reg & 3) + 8 * (reg >> 2);
                float x = acc[fm][fn][reg] + bv;
                if (act) x = tanhf(x);
                C[(size_t)row * N + col] = x;
            }
        }
    }
}

// ---------------- LSTM gate: consumes G f32 (M x 2048), writes c f32 + h planes ----------------
__global__ void lstm_gate(const float* __restrict__ G,
                          const float* __restrict__ gtab, const int* __restrict__ gidx, int gstride,
                          const float* __restrict__ ba, const float* __restrict__ bb,
                          float* __restrict__ c_state,
                          short* __restrict__ hpl, size_t hps,
                          short* __restrict__ cpl, size_t cps, int copyMul, int copyAdd,
                          int M)
{
    int idx = blockIdx.x * 256 + threadIdx.x;
    if (idx >= M * HD) return;
    int m = idx >> 9, u = idx & 511;
    const float* g = G + (size_t)m * G4H;
    float gi = g[u], gf = g[u + 512], gg = g[u + 1024], go = g[u + 1536];
    if (gtab) {
        int id = gidx[(size_t)m * gstride];
        const float* a = gtab + (size_t)id * G4H;
        gi += a[u]; gf += a[u + 512]; gg += a[u + 1024]; go += a[u + 1536];
    }
    gi += ba[u];        gf += ba[u + 512];  gg += ba[u + 1024]; go += ba[u + 1536];
    gi += bb[u];        gf += bb[u + 512];  gg += bb[u + 1024]; go += bb[u + 1536];
    float c = sigmoidf_(gf) * c_state[idx] + sigmoidf_(gi) * tanhf(gg);
    c_state[idx] = c;
    float h = sigmoidf_(go) * tanhf(c);
    short hh, hm, hl; split3(h, hh, hm, hl);
    size_t o = offf(m, u);
    hpl[o] = hh; hpl[hps + o] = hm; hpl[2 * hps + o] = hl;
    if (cpl) {
        size_t o2 = offf(m * copyMul + copyAdd, u);
        cpl[o2] = hh; cpl[cps + o2] = hm; cpl[2 * cps + o2] = hl;
    }
}

// ---------------- splits ----------------
__global__ void split_ci(const float* __restrict__ ci, short* __restrict__ h1pl, short* __restrict__ h2pl,
                         size_t ps, float* __restrict__ c1, float* __restrict__ c2)
{
    int idx = blockIdx.x * 256 + threadIdx.x;  // B*H
    int b = idx >> 9, u = idx & 511;
    const float* r = ci + (size_t)b * G4H;
    size_t o = offf(b, u);
    short h, m, l;
    split3(r[u], h, m, l);        h1pl[o] = h; h1pl[ps + o] = m; h1pl[2 * ps + o] = l;
    split3(r[u + 512], h, m, l);  h2pl[o] = h; h2pl[ps + o] = m; h2pl[2 * ps + o] = l;
    c1[idx] = r[u + 1024]; c2[idx] = r[u + 1536];
}

__global__ void split_states(const float* __restrict__ st, short* __restrict__ h0pl, short* __restrict__ h1dpl,
                             short* __restrict__ hipl, size_t ps,
                             float* __restrict__ c0, float* __restrict__ c1d)
{
    int idx = blockIdx.x * 256 + threadIdx.x;  // MDEC*H
    int m = idx >> 9, u = idx & 511;
    const float* r = st + (size_t)m * G4H;
    float a = r[u], b = r[u + 512];
    size_t o = offf(m, u);
    short h, mm, l;
    split3(a, h, mm, l);      h0pl[o] = h;  h0pl[ps + o] = mm;  h0pl[2 * ps + o] = l;
    split3(b, h, mm, l);      h1dpl[o] = h; h1dpl[ps + o] = mm; h1dpl[2 * ps + o] = l;
    split3(a + b, h, mm, l);  hipl[o] = h;  hipl[ps + o] = mm;  hipl[2 * ps + o] = l;
    c0[idx] = r[u + 1024]; c1d[idx] = r[u + 1536];
}

// ---------------- bias + softmax over V=512 ----------------
__global__ void softmax_out(const float* __restrict__ L, const float* __restrict__ bo,
                            float* __restrict__ out, int t)
{
    int m = blockIdx.x, tid = threadIdx.x;
    float x0 = L[(size_t)m * VVV + tid]       + bo[tid];
    float x1 = L[(size_t)m * VVV + tid + 256] + bo[tid + 256];
    float mx = fmaxf(x0, x1);
    #pragma unroll
    for (int off = 32; off; off >>= 1) mx = fmaxf(mx, __shfl_xor(mx, off));
    __shared__ float sm[4], ss[4];
    if ((tid & 63) == 0) sm[tid >> 6] = mx;
    __syncthreads();
    mx = fmaxf(fmaxf(sm[0], sm[1]), fmaxf(sm[2], sm[3]));
    float e0 = expf(x0 - mx), e1 = expf(x1 - mx);
    float s = e0 + e1;
    #pragma unroll
    for (int off = 32; off; off >>= 1) s += __shfl_xor(s, off);
    if ((tid & 63) == 0) ss[tid >> 6] = s;
    __syncthreads();
    s = ss[0] + ss[1] + ss[2] + ss[3];
    float inv = 1.f / s;
    float* o = out + ((size_t)m * TTT + t) * VVV;
    o[tid] = e0 * inv;
    o[tid + 256] = e1 * inv;
}

// ---------------- host ----------------
extern "C" void kernel_launch(void* const* d_in, const int* in_sizes, int n_in,
                              void* d_out, int out_size, void* d_ws, size_t ws_size,
                              hipStream_t stream)
{
    const float* z     = (const float*)d_in[0];
    const int*   x     = (const int*)  d_in[1];
    const float* Wc    = (const float*)d_in[2];
    const float* bc    = (const float*)d_in[3];
    const float* cWih0 = (const float*)d_in[4];
    const float* cWhh0 = (const float*)d_in[5];
    const float* cbih0 = (const float*)d_in[6];
    const float* cbhh0 = (const float*)d_in[7];
    const float* cWih1 = (const float*)d_in[8];
    const float* cWhh1 = (const float*)d_in[9];
    const float* cbih1 = (const float*)d_in[10];
    const float* cbhh1 = (const float*)d_in[11];
    const float* Wd    = (const float*)d_in[12];
    const float* bd    = (const float*)d_in[13];
    const float* dWih0 = (const float*)d_in[14];
    const float* dWhh0 = (const float*)d_in[15];
    const float* dbih0 = (const float*)d_in[16];
    const float* dbhh0 = (const float*)d_in[17];
    const float* dWih1 = (const float*)d_in[18];
    const float* dWhh1 = (const float*)d_in[19];
    const float* dbih1 = (const float*)d_in[20];
    const float* dbhh1 = (const float*)d_in[21];
    const float* emb   = (const float*)d_in[22];
    const float* Wo    = (const float*)d_in[23];
    const float* bo    = (const float*)d_in[24];
    float* out = (float*)d_out;
    (void)in_sizes; (void)n_in; (void)out_size; (void)ws_size;

    char* wsb = (char*)d_ws;
    size_t off = 0;
    auto alloc = [&](size_t bytes) -> void* {
        off = (off + 255) & ~(size_t)255;
        void* p = wsb + off;
        off += bytes;
        return p;
    };
    const size_t PW  = (size_t)G4H * 512;       // weight plane elements (N=2048,K=512)
    const size_t PWo = (size_t)512 * 512;
    const size_t PA4 = (size_t)MDEC * 512;      // M=4096 A-plane elements
    const size_t PAB = (size_t)BB * 512;        // M=256
    const size_t PAe = (size_t)512 * 512;       // M=512 (emb)

    short* WcTp    = (short*)alloc(3 * PW * 2);
    short* cWih0Tp = (short*)alloc(3 * PW * 2);
    short* cWhh0Tp = (short*)alloc(3 * PW * 2);
    short* cWih1Tp = (short*)alloc(3 * PW * 2);
    short* cWhh1Tp = (short*)alloc(3 * PW * 2);
    short* WdTp    = (short*)alloc(3 * PW * 2);
    short* dW1Tp   = (short*)alloc(3 * PW * 2);
    short* dW2Tp   = (short*)alloc(3 * PW * 2);
    short* dWhh0Tp = (short*)alloc(3 * PW * 2);
    short* dWih1Tp = (short*)alloc(3 * PW * 2);
    short* dWhh1Tp = (short*)alloc(3 * PW * 2);
    short* WoTp    = (short*)alloc(3 * PWo * 2);
    short* zpl     = (short*)alloc(3 * PAB * 2);
    short* embpl   = (short*)alloc(3 * PAe * 2);
    float* embW0   = (float*)alloc((size_t)VVV * G4H * 4);
    float* Gbuf    = (float*)alloc((size_t)MDEC * G4H * 4);
    short* h1pl    = (short*)alloc(3 * PAB * 2);
    short* h2pl    = (short*)alloc(3 * PAB * 2);
    float* c1      = (float*)alloc((size_t)BB * HD * 4);
    float* c2      = (float*)alloc((size_t)BB * HD * 4);
    short* h0pl    = (short*)alloc(3 * PA4 * 2);   // also aliases cond planes
    short* h1dpl   = (short*)alloc(3 * PA4 * 2);
    short* hipl    = (short*)alloc(3 * PA4 * 2);
    float* c0      = (float*)alloc((size_t)MDEC * HD * 4);
    float* c1d     = (float*)alloc((size_t)MDEC * HD * 4);
    short* condpl  = h0pl;                          // alias: cond consumed before h0pl written
    float* ci      = Gbuf;                          // alias: ci consumed before Gbuf reused

    auto TS = [&](const float* W, short* pl, int N, int ldw, int col0) {
        int total = N * 512;
        transpose_split<<<dim3((total + 255) / 256), dim3(256), 0, stream>>>(W, pl, PW * (N == 512 ? 0 : 0) + (size_t)N * 512, ldw, col0, total);
    };
    // (plane stride = N*512 elements)
    TS(Wc,    WcTp,    2048, 512,  0);
    TS(cWih0, cWih0Tp, 2048, 512,  0);
    TS(cWhh0, cWhh0Tp, 2048, 512,  0);
    TS(cWih1, cWih1Tp, 2048, 512,  0);
    TS(cWhh1, cWhh1Tp, 2048, 512,  0);
    TS(Wd,    WdTp,    2048, 512,  0);
    TS(dWih0, dW1Tp,   2048, 1024, 0);
    TS(dWih0, dW2Tp,   2048, 1024, 512);
    TS(dWhh0, dWhh0Tp, 2048, 512,  0);
    TS(dWih1, dWih1Tp, 2048, 512,  0);
    TS(dWhh1, dWhh1Tp, 2048, 512,  0);
    TS(Wo,    WoTp,    512,  512,  0);

    auto MF = [&](const short* A1, const short* B1, const short* A2, const short* B2,
                  const float* bias, int act, float* C, int M, int N, int pairs) {
        dim3 g(N / 128, M / 128);
        mfma6_gemm<<<g, dim3(256), 0, stream>>>(A1, B1, A2, B2, bias, act, C, M, N, pairs * 32);
    };
    auto GATE = [&](const float* G, const float* gtab, const int* gidx, int gstride,
                    const float* ba, const float* bb, float* c_state,
                    short* hpl, size_t hps, short* cpl, size_t cps, int cMul, int cAdd, int M) {
        lstm_gate<<<dim3((M * HD) / 256), dim3(256), 0, stream>>>(
            G, gtab, gidx, gstride, ba, bb, c_state, hpl, hps, cpl, cps, cMul, cAdd, M);
    };

    // Phase A: ci = tanh(z @ Wc.T + bc)
    convert_planes<<<dim3((BB * 512) / 256), dim3(256), 0, stream>>>(z, zpl, PAB, BB * 512);
    MF(zpl, WcTp, nullptr, nullptr, bc, 1, ci, BB, G4H, 1);
    split_ci<<<dim3(BB * HD / 256), dim3(256), 0, stream>>>(ci, h1pl, h2pl, PAB, c1, c2);

    // embW0 = emb @ dWih0[:, :512].T
    convert_planes<<<dim3((512 * 512) / 256), dim3(256), 0, stream>>>(emb, embpl, PAe, 512 * 512);
    MF(embpl, dW1Tp, nullptr, nullptr, nullptr, 0, embW0, 512, G4H, 1);

    // Phase B: conditioning LSTM (M=256), 16 steps x 2 cells
    for (int u = 0; u < UU; ++u) {
        if (u == 0)
            MF(h1pl, cWhh0Tp, nullptr, nullptr, nullptr, 0, Gbuf, BB, G4H, 1);
        else
            MF(h2pl, cWih0Tp, h1pl, cWhh0Tp, nullptr, 0, Gbuf, BB, G4H, 2);
        GATE(Gbuf, nullptr, nullptr, 0, cbih0, cbhh0, c1, h1pl, PAB, nullptr, 0, 0, 0, BB);
        MF(h1pl, cWih1Tp, h2pl, cWhh1Tp, nullptr, 0, Gbuf, BB, G4H, 2);
        GATE(Gbuf, nullptr, nullptr, 0, cbih1, cbhh1, c2, h2pl, PAB, condpl, PA4, UU, u, BB);
    }

    // Phase C: states = tanh(cond @ Wd.T + bd) -> decoder init states + h_init planes
    MF(condpl, WdTp, nullptr, nullptr, bd, 1, Gbuf, MDEC, G4H, 1);
    split_states<<<dim3((MDEC * HD) / 256), dim3(256), 0, stream>>>(Gbuf, h0pl, h1dpl, hipl, PA4, c0, c1d);

    // Phase D: decoder, 16 steps
    for (int t = 0; t < TTT; ++t) {
        // layer 0: g = h0 @ dWhh0.T + hinit @ dWih0[:,512:].T (+ emb gather + biases in gate)
        MF(h0pl, dWhh0Tp, hipl, dW2Tp, nullptr, 0, Gbuf, MDEC, G4H, 2);
        GATE(Gbuf, t > 0 ? embW0 : nullptr, t > 0 ? x + (t - 1) : nullptr, TTT,
             dbih0, dbhh0, c0, h0pl, PA4, nullptr, 0, 0, 0, MDEC);
        // layer 1
        MF(h0pl, dWih1Tp, h1dpl, dWhh1Tp, nullptr, 0, Gbuf, MDEC, G4H, 2);
        GATE(Gbuf, nullptr, nullptr, 0, dbih1, dbhh1, c1d, h1dpl, PA4, nullptr, 0, 0, 0, MDEC);
        // logits + softmax
        MF(h1dpl, WoTp, nullptr, nullptr, nullptr, 0, Gbuf, MDEC, VVV, 1);
        softmax_out<<<dim3(MDEC), dim3(256), 0, stream>>>(Gbuf, bo, out, t);
    }
}

// Round 3
// 4186.033 us; speedup vs baseline: 3.2798x; 1.3612x over previous
//
#include <hip/hip_runtime.h>
#include <math.h>

#define HD   512
#define G4H  2048
#define BB   256
#define UU   16
#define TTT  16
#define VVV  512
#define MDEC 4096   // B*U

#define AS1 __attribute__((address_space(1)))
#define AS3 __attribute__((address_space(3)))

typedef __attribute__((ext_vector_type(8))) short short8v;
typedef __attribute__((ext_vector_type(16))) float f32x16;

__device__ __forceinline__ float sigmoidf_(float x) { return 1.f / (1.f + expf(-x)); }

__device__ __forceinline__ unsigned short f2bf(float f) {
    unsigned int u = __float_as_uint(f);
    unsigned int r = (u + 0x7FFF + ((u >> 16) & 1)) >> 16;
    return (unsigned short)r;
}
__device__ __forceinline__ float bf2f(unsigned short s) {
    return __uint_as_float(((unsigned int)s) << 16);
}

// fragment-ready offset for element (m,k), K=512 fixed:
// off = ((m>>5)*64 + (k>>3))*256 + (m&31)*8 + (k&7)
__device__ __forceinline__ size_t offf(int m, int k) {
    return ((size_t)((m >> 5) * 64 + (k >> 3))) * 256 + (size_t)((m & 31) * 8 + (k & 7));
}

// ---------------- transpose + np-way split: W (N x ldw) -> blocked bf16 planes ----------------
__global__ void transpose_split(const float* __restrict__ Wsrc, short* __restrict__ pl, size_t ps,
                                int np, int ldw, int col0, int total)
{
    int o = blockIdx.x * 256 + threadIdx.x;
    if (o >= total) return;
    int c = o >> 8, w = o & 255, r = w >> 3, j = w & 7;
    int n = (c >> 6) * 32 + r, k = (c & 63) * 8 + j;
    float rem = Wsrc[(size_t)n * ldw + col0 + k];
    for (int p = 0; p < np; ++p) {
        unsigned short b = f2bf(rem);
        pl[(size_t)p * ps + o] = (short)b;
        rem -= bf2f(b);
    }
}

// ---------------- f32 row-major (M x 512) -> blocked bf16 planes ----------------
__global__ void convert_planes(const float* __restrict__ in, short* __restrict__ pl, size_t ps,
                               int np, int total)
{
    int o = blockIdx.x * 256 + threadIdx.x;
    if (o >= total) return;
    int c = o >> 8, w = o & 255, r = w >> 3, j = w & 7;
    int m = (c >> 6) * 32 + r, k = (c & 63) * 8 + j;
    float rem = in[(size_t)m * 512 + k];
    for (int p = 0; p < np; ++p) {
        unsigned short b = f2bf(rem);
        pl[(size_t)p * ps + o] = (short)b;
        rem -= bf2f(b);
    }
}

// ---------------- MFMA GEMM ----------------
// C[MxN] = act( sum_pairs A_p(MxK=512) * B_p(512xN) + bias + addC )
// PLANES=2 -> 3 products (hh,hl,lh), 3-buffer counted-vmcnt pipeline.
// PLANES=3 -> 6 products, 2-buffer drain pipeline (used for one-time / accuracy-critical GEMMs).
// Block: 512 thr = 8 waves (4m x 2n), tile 256x128, wave tile 64x64, BK=32.
template<int PLANES>
__global__ __launch_bounds__(512, 2) void mfma_gemm(
    const short* __restrict__ A1, const short* __restrict__ B1,
    const short* __restrict__ A2, const short* __restrict__ B2,
    const float* __restrict__ bias, const float* __restrict__ addC, int act,
    float* __restrict__ C, int M, int N, int nsteps)
{
    constexpr int NBUF   = (PLANES == 2) ? 3 : 2;
    constexpr int CPW    = 3 * PLANES;          // staging chunks per wave per buffer
    constexpr int CHUNKS = CPW * 8;             // 48 (P=2) or 72 (P=3)
    constexpr int BUFSH  = CHUNKS * 512;        // shorts per buffer
    __shared__ __align__(16) short lds[NBUF * BUFSH];   // 144 KB either way

    const int tid = threadIdx.x, lane = tid & 63, wid = tid >> 6;
    const int wm = wid >> 1, wn = wid & 1;
    const int l31 = lane & 31, loct = lane >> 5;

    // XCD-bijective chunked swizzle (m204): same-A-row blocks land on one XCD
    const int nwg = gridDim.x * gridDim.y;
    const int d = blockIdx.y * gridDim.x + blockIdx.x;
    const int q = nwg >> 3, r = nwg & 7, xcd = d & 7, pos = d >> 3;
    const int logical = (xcd < r ? xcd * (q + 1) : r * (q + 1) + (xcd - r) * q) + pos;
    const int bx = logical % gridDim.x, by = logical / gridDim.x;

    const int mblk0 = by * 8, nblk0 = bx * 4;   // 32-row/col blocks
    const size_t planeA = (size_t)M * 512, planeB = (size_t)N * 512;

    const short* cur[CPW];
    const short* nxt[CPW];
    int ldo[CPW];
    #pragma unroll
    for (int i = 0; i < CPW; ++i) {
        int c = wid * CPW + i;
        ldo[i] = c * 512;
        size_t off;
        const short *b1, *b2;
        if (c < PLANES * 16) {                  // A side
            int plane = c >> 4, rem = c & 15, blk = rem >> 1, piece = rem & 1;
            off = (size_t)plane * planeA + (size_t)(mblk0 + blk) * 16384 + piece * 512 + lane * 8;
            b1 = A1; b2 = A2;
        } else {                                // B side
            int cb = c - PLANES * 16;
            int plane = cb >> 3, rem = cb & 7, blk = rem >> 1, piece = rem & 1;
            off = (size_t)plane * planeB + (size_t)(nblk0 + blk) * 16384 + piece * 512 + lane * 8;
            b1 = B1; b2 = B2;
        }
        cur[i] = b1 + off;
        nxt[i] = b2 ? (b2 + off) : (b1 + off);
    }

    f32x16 acc[2][2] = {};

    auto STAGE = [&](int bufIdx) {
        short* db = &lds[bufIdx * BUFSH];
        #pragma unroll
        for (int i = 0; i < CPW; ++i) {
            __builtin_amdgcn_global_load_lds((const AS1 unsigned int*)cur[i],
                                             (AS3 unsigned int*)(db + ldo[i]), 16, 0, 0);
            cur[i] += 1024;
        }
    };

    // prologue
    if constexpr (NBUF == 3) {
        STAGE(0); STAGE(1);
        asm volatile("s_waitcnt vmcnt(%0)" :: "n"(CPW) : "memory");
    } else {
        STAGE(0);
        asm volatile("s_waitcnt vmcnt(0)" ::: "memory");
    }
    __builtin_amdgcn_s_barrier();

    for (int t = 0; t < nsteps; ++t) {
        int s = t + NBUF - 1;
        if (s < nsteps) {
            if (s == 16) {                      // pair switch (dual-pair calls only)
                #pragma unroll
                for (int i = 0; i < CPW; ++i) cur[i] = nxt[i];
            }
            STAGE(s % NBUF);
        }
        {
            const short* L = &lds[(t % NBUF) * BUFSH];
            #pragma unroll
            for (int ksub = 0; ksub < 2; ++ksub) {
                short8v a[2][PLANES], b[2][PLANES];
                #pragma unroll
                for (int p = 0; p < PLANES; ++p) {
                    #pragma unroll
                    for (int f = 0; f < 2; ++f) {
                        a[f][p] = *(const short8v*)(L + (p * 16 + (wm * 2 + f) * 2 + ksub) * 512
                                                      + loct * 256 + l31 * 8);
                        b[f][p] = *(const short8v*)(L + PLANES * 8192
                                                      + (p * 8 + (wn * 2 + f) * 2 + ksub) * 512
                                                      + loct * 256 + l31 * 8);
                    }
                }
                #define PRODX(pa, pb) \
                    acc[0][0] = __builtin_amdgcn_mfma_f32_32x32x16_bf16(a[0][pa], b[0][pb], acc[0][0], 0,0,0); \
                    acc[0][1] = __builtin_amdgcn_mfma_f32_32x32x16_bf16(a[0][pa], b[1][pb], acc[0][1], 0,0,0); \
                    acc[1][0] = __builtin_amdgcn_mfma_f32_32x32x16_bf16(a[1][pa], b[0][pb], acc[1][0], 0,0,0); \
                    acc[1][1] = __builtin_amdgcn_mfma_f32_32x32x16_bf16(a[1][pa], b[1][pb], acc[1][1], 0,0,0);
                if constexpr (PLANES == 2) {
                    PRODX(0, 0) PRODX(0, 1) PRODX(1, 0)
                } else {
                    PRODX(0, 0) PRODX(0, 1) PRODX(1, 0) PRODX(1, 1) PRODX(0, 2) PRODX(2, 0)
                }
                #undef PRODX
            }
        }
        if constexpr (NBUF == 3) {
            if (t + 2 < nsteps)
                asm volatile("s_waitcnt vmcnt(%0) lgkmcnt(0)" :: "n"(CPW) : "memory");
            else
                asm volatile("s_waitcnt vmcnt(0) lgkmcnt(0)" ::: "memory");
        } else {
            asm volatile("s_waitcnt vmcnt(0) lgkmcnt(0)" ::: "memory");
        }
        __builtin_amdgcn_s_barrier();
    }

    // epilogue: C/D layout col=lane&31, row=(reg&3)+8*(reg>>2)+4*(lane>>5)
    #pragma unroll
    for (int fm = 0; fm < 2; ++fm) {
        #pragma unroll
        for (int fn = 0; fn < 2; ++fn) {
            int col = bx * 128 + wn * 64 + fn * 32 + l31;
            float bv = bias ? bias[col] : 0.f;
            int rbase = by * 256 + wm * 64 + fm * 32 + 4 * loct;
            #pragma unroll
            for (int reg = 0; reg < 16; ++reg) {
                int row = rbase + (reg & 3) + 8 * (reg >> 2);
                float xv = acc[fm][fn][reg] + bv;
                if (addC) xv += addC[(size_t)row * N + col];
                if (act) xv = tanhf(xv);
                C[(size_t)row * N + col] = xv;
            }
        }
    }
}

// ---------------- LSTM gate: consumes G f32 (M x 2048), writes c f32 + h planes (2) ----------------
__global__ void lstm_gate(const float* __restrict__ G,
                          const float* __restrict__ gtab, const int* __restrict__ gidx, int gstride,
                          const float* __restrict__ ba, const float* __restrict__ bb,
                          float* __restrict__ c_state,
                          short* __restrict__ hpl, size_t hps,
                          short* __restrict__ cpl, size_t cps, int copyMul, int copyAdd,
                          int M)
{
    int idx = blockIdx.x * 256 + threadIdx.x;
    if (idx >= M * HD) return;
    int m = idx >> 9, u = idx & 511;
    const float* g = G + (size_t)m * G4H;
    float gi = g[u], gf = g[u + 512], gg = g[u + 1024], go = g[u + 1536];
    if (gtab) {
        int id = gidx[(size_t)m * gstride];
        const float* a = gtab + (size_t)id * G4H;
        gi += a[u]; gf += a[u + 512]; gg += a[u + 1024]; go += a[u + 1536];
    }
    gi += ba[u];       gf += ba[u + 512]; gg += ba[u + 1024]; go += ba[u + 1536];
    gi += bb[u];       gf += bb[u + 512]; gg += bb[u + 1024]; go += bb[u + 1536];
    float c = sigmoidf_(gf) * c_state[idx] + sigmoidf_(gi) * tanhf(gg);
    c_state[idx] = c;
    float h = sigmoidf_(go) * tanhf(c);
    float rem = h;
    unsigned short b0 = f2bf(rem); rem -= bf2f(b0);
    unsigned short b1 = f2bf(rem); rem -= bf2f(b1);
    size_t o = offf(m, u);
    hpl[o] = (short)b0; hpl[hps + o] = (short)b1;
    if (cpl) {
        unsigned short b2 = f2bf(rem);
        size_t o2 = offf(m * copyMul + copyAdd, u);
        cpl[o2] = (short)b0; cpl[cps + o2] = (short)b1; cpl[2 * cps + o2] = (short)b2;
    }
}

// ---------------- splits ----------------
__global__ void split_ci(const float* __restrict__ ci, short* __restrict__ h1pl, short* __restrict__ h2pl,
                         size_t ps, float* __restrict__ c1, float* __restrict__ c2)
{
    int idx = blockIdx.x * 256 + threadIdx.x;  // B*H
    int b = idx >> 9, u = idx & 511;
    const float* rr = ci + (size_t)b * G4H;
    size_t o = offf(b, u);
    float rem = rr[u];
    unsigned short x0 = f2bf(rem); rem -= bf2f(x0);
    h1pl[o] = (short)x0; h1pl[ps + o] = (short)f2bf(rem);
    rem = rr[u + 512];
    x0 = f2bf(rem); rem -= bf2f(x0);
    h2pl[o] = (short)x0; h2pl[ps + o] = (short)f2bf(rem);
    c1[idx] = rr[u + 1024]; c2[idx] = rr[u + 1536];
}

__global__ void split_states(const float* __restrict__ st, short* __restrict__ h0pl, short* __restrict__ h1dpl,
                             short* __restrict__ hipl, size_t ps2, size_t ps3,
                             float* __restrict__ c0, float* __restrict__ c1d)
{
    int idx = blockIdx.x * 256 + threadIdx.x;  // MDEC*H
    int m = idx >> 9, u = idx & 511;
    const float* rr = st + (size_t)m * G4H;
    float a = rr[u], b = rr[u + 512];
    size_t o = offf(m, u);
    float rem = a;
    unsigned short x0 = f2bf(rem); rem -= bf2f(x0);
    h0pl[o] = (short)x0; h0pl[ps2 + o] = (short)f2bf(rem);
    rem = b;
    x0 = f2bf(rem); rem -= bf2f(x0);
    h1dpl[o] = (short)x0; h1dpl[ps2 + o] = (short)f2bf(rem);
    rem = a + b;
    x0 = f2bf(rem); rem -= bf2f(x0);
    hipl[o] = (short)x0;
    unsigned short x1 = f2bf(rem); rem -= bf2f(x1);
    hipl[ps3 + o] = (short)x1; hipl[2 * ps3 + o] = (short)f2bf(rem);
    c0[idx] = rr[u + 1024]; c1d[idx] = rr[u + 1536];
}

// ---------------- bias + softmax over V=512 ----------------
__global__ void softmax_out(const float* __restrict__ L, const float* __restrict__ bo,
                            float* __restrict__ out, int t)
{
    int m = blockIdx.x, tid = threadIdx.x;
    float x0 = L[(size_t)m * VVV + tid]       + bo[tid];
    float x1 = L[(size_t)m * VVV + tid + 256] + bo[tid + 256];
    float mx = fmaxf(x0, x1);
    #pragma unroll
    for (int off = 32; off; off >>= 1) mx = fmaxf(mx, __shfl_xor(mx, off));
    __shared__ float sm[4], ss[4];
    if ((tid & 63) == 0) sm[tid >> 6] = mx;
    __syncthreads();
    mx = fmaxf(fmaxf(sm[0], sm[1]), fmaxf(sm[2], sm[3]));
    float e0 = expf(x0 - mx), e1 = expf(x1 - mx);
    float s = e0 + e1;
    #pragma unroll
    for (int off = 32; off; off >>= 1) s += __shfl_xor(s, off);
    if ((tid & 63) == 0) ss[tid >> 6] = s;
    __syncthreads();
    s = ss[0] + ss[1] + ss[2] + ss[3];
    float inv = 1.f / s;
    float* o = out + ((size_t)m * TTT + t) * VVV;
    o[tid] = e0 * inv;
    o[tid + 256] = e1 * inv;
}

// ---------------- host ----------------
extern "C" void kernel_launch(void* const* d_in, const int* in_sizes, int n_in,
                              void* d_out, int out_size, void* d_ws, size_t ws_size,
                              hipStream_t stream)
{
    const float* z     = (const float*)d_in[0];
    const int*   x     = (const int*)  d_in[1];
    const float* Wc    = (const float*)d_in[2];
    const float* bc    = (const float*)d_in[3];
    const float* cWih0 = (const float*)d_in[4];
    const float* cWhh0 = (const float*)d_in[5];
    const float* cbih0 = (const float*)d_in[6];
    const float* cbhh0 = (const float*)d_in[7];
    const float* cWih1 = (const float*)d_in[8];
    const float* cWhh1 = (const float*)d_in[9];
    const float* cbih1 = (const float*)d_in[10];
    const float* cbhh1 = (const float*)d_in[11];
    const float* Wd    = (const float*)d_in[12];
    const float* bd    = (const float*)d_in[13];
    const float* dWih0 = (const float*)d_in[14];
    const float* dWhh0 = (const float*)d_in[15];
    const float* dbih0 = (const float*)d_in[16];
    const float* dbhh0 = (const float*)d_in[17];
    const float* dWih1 = (const float*)d_in[18];
    const float* dWhh1 = (const float*)d_in[19];
    const float* dbih1 = (const float*)d_in[20];
    const float* dbhh1 = (const float*)d_in[21];
    const float* emb   = (const float*)d_in[22];
    const float* Wo    = (const float*)d_in[23];
    const float* bo    = (const float*)d_in[24];
    float* out = (float*)d_out;
    (void)in_sizes; (void)n_in; (void)out_size; (void)ws_size;

    char* wsb = (char*)d_ws;
    size_t off = 0;
    auto alloc = [&](size_t bytes) -> void* {
        off = (off + 255) & ~(size_t)255;
        void* p = wsb + off;
        off += bytes;
        return p;
    };
    const size_t PW  = (size_t)G4H * 512;   // weight plane elems (N=2048)
    const size_t PWo = (size_t)512 * 512;
    const size_t PA4 = (size_t)MDEC * 512;
    const size_t PAB = (size_t)BB * 512;
    const size_t PAe = (size_t)512 * 512;

    // 3-plane weights (6-product consumers)
    short* WcTp    = (short*)alloc(3 * PW * 2);
    short* WdTp    = (short*)alloc(3 * PW * 2);
    short* dW1Tp   = (short*)alloc(3 * PW * 2);
    short* dW2Tp   = (short*)alloc(3 * PW * 2);
    // 2-plane weights (3-product consumers)
    short* cWih0Tp = (short*)alloc(2 * PW * 2);
    short* cWhh0Tp = (short*)alloc(2 * PW * 2);
    short* cWih1Tp = (short*)alloc(2 * PW * 2);
    short* cWhh1Tp = (short*)alloc(2 * PW * 2);
    short* dWhh0Tp = (short*)alloc(2 * PW * 2);
    short* dWih1Tp = (short*)alloc(2 * PW * 2);
    short* dWhh1Tp = (short*)alloc(2 * PW * 2);
    short* WoTp    = (short*)alloc(2 * PWo * 2);
    short* zpl     = (short*)alloc(3 * PAB * 2);
    short* embpl   = (short*)alloc(3 * PAe * 2);
    float* embW0   = (float*)alloc((size_t)VVV * G4H * 4);
    float* Gbuf    = (float*)alloc((size_t)MDEC * G4H * 4);
    float* hinitg  = (float*)alloc((size_t)MDEC * G4H * 4);
    short* h1pl    = (short*)alloc(2 * PAB * 2);
    short* h2pl    = (short*)alloc(2 * PAB * 2);
    float* c1      = (float*)alloc((size_t)BB * HD * 4);
    float* c2      = (float*)alloc((size_t)BB * HD * 4);
    short* condpl  = (short*)alloc(3 * PA4 * 2);  // 3-plane; later reused as hipl
    short* h0pl    = (short*)alloc(2 * PA4 * 2);
    short* h1dpl   = (short*)alloc(2 * PA4 * 2);
    float* c0      = (float*)alloc((size_t)MDEC * HD * 4);
    float* c1d     = (float*)alloc((size_t)MDEC * HD * 4);
    short* hipl    = condpl;                      // alias: condpl dead after phase C GEMM
    float* ci      = Gbuf;                        // alias: ci consumed before Gbuf reuse

    auto TS = [&](const float* W, short* pl, int np, int N, int ldw, int col0) {
        int total = N * 512;
        transpose_split<<<dim3((total + 255) / 256), dim3(256), 0, stream>>>(
            W, pl, (size_t)N * 512, np, ldw, col0, total);
    };
    TS(Wc,    WcTp,    3, 2048, 512,  0);
    TS(Wd,    WdTp,    3, 2048, 512,  0);
    TS(dWih0, dW1Tp,   3, 2048, 1024, 0);
    TS(dWih0, dW2Tp,   3, 2048, 1024, 512);
    TS(cWih0, cWih0Tp, 2, 2048, 512,  0);
    TS(cWhh0, cWhh0Tp, 2, 2048, 512,  0);
    TS(cWih1, cWih1Tp, 2, 2048, 512,  0);
    TS(cWhh1, cWhh1Tp, 2, 2048, 512,  0);
    TS(dWhh0, dWhh0Tp, 2, 2048, 512,  0);
    TS(dWih1, dWih1Tp, 2, 2048, 512,  0);
    TS(dWhh1, dWhh1Tp, 2, 2048, 512,  0);
    TS(Wo,    WoTp,    2, 512,  512,  0);

    auto MF2 = [&](const short* A1, const short* B1, const short* A2, const short* B2,
                   const float* bias, const float* addC, int act, float* Cc, int M_, int N_, int steps) {
        dim3 g(N_ / 128, M_ / 256);
        mfma_gemm<2><<<g, dim3(512), 0, stream>>>(A1, B1, A2, B2, bias, addC, act, Cc, M_, N_, steps);
    };
    auto MF6 = [&](const short* A1, const short* B1,
                   const float* bias, int act, float* Cc, int M_, int N_) {
        dim3 g(N_ / 128, M_ / 256);
        mfma_gemm<3><<<g, dim3(512), 0, stream>>>(A1, B1, nullptr, nullptr, bias, nullptr, act, Cc, M_, N_, 16);
    };
    auto GATE = [&](const float* G, const float* gtab, const int* gidx, int gstride,
                    const float* ba, const float* bb, float* c_state,
                    short* hpl, size_t hps, short* cpl, size_t cps, int cMul, int cAdd, int M_) {
        lstm_gate<<<dim3((M_ * HD) / 256), dim3(256), 0, stream>>>(
            G, gtab, gidx, gstride, ba, bb, c_state, hpl, hps, cpl, cps, cMul, cAdd, M_);
    };

    // Phase A: ci = tanh(z @ Wc.T + bc)   [6p]
    convert_planes<<<dim3((BB * 512) / 256), dim3(256), 0, stream>>>(z, zpl, PAB, 3, BB * 512);
    MF6(zpl, WcTp, bc, 1, ci, BB, G4H);
    split_ci<<<dim3(BB * HD / 256), dim3(256), 0, stream>>>(ci, h1pl, h2pl, PAB, c1, c2);

    // embW0 = emb @ dWih0[:, :512].T   [6p, one-time]
    convert_planes<<<dim3((512 * 512) / 256), dim3(256), 0, stream>>>(emb, embpl, PAe, 3, 512 * 512);
    MF6(embpl, dW1Tp, nullptr, 0, embW0, 512, G4H);

    // Phase B: conditioning LSTM (M=256), 16 steps x 2 cells   [3p]
    for (int u = 0; u < UU; ++u) {
        if (u == 0)
            MF2(h1pl, cWhh0Tp, nullptr, nullptr, nullptr, nullptr, 0, Gbuf, BB, G4H, 16);
        else
            MF2(h2pl, cWih0Tp, h1pl, cWhh0Tp, nullptr, nullptr, 0, Gbuf, BB, G4H, 32);
        GATE(Gbuf, nullptr, nullptr, 0, cbih0, cbhh0, c1, h1pl, PAB, nullptr, 0, 0, 0, BB);
        MF2(h1pl, cWih1Tp, h2pl, cWhh1Tp, nullptr, nullptr, 0, Gbuf, BB, G4H, 32);
        GATE(Gbuf, nullptr, nullptr, 0, cbih1, cbhh1, c2, h2pl, PAB, condpl, PA4, UU, u, BB);
    }

    // Phase C: states = tanh(cond @ Wd.T + bd)   [6p]
    MF6(condpl, WdTp, bd, 1, Gbuf, MDEC, G4H);
    split_states<<<dim3((MDEC * HD) / 256), dim3(256), 0, stream>>>(
        Gbuf, h0pl, h1dpl, hipl, PA4, PA4, c0, c1d);

    // hinitg = hinit @ dWih0[:,512:].T   [6p, one-time; consumed by L0 epilogue]
    MF6(hipl, dW2Tp, nullptr, 0, hinitg, MDEC, G4H);

    // Phase D: decoder, 16 steps   [3p]
    for (int t = 0; t < TTT; ++t) {
        // layer 0: g = h0 @ dWhh0.T + hinitg (epilogue) (+ emb gather + biases in gate)
        MF2(h0pl, dWhh0Tp, nullptr, nullptr, nullptr, hinitg, 0, Gbuf, MDEC, G4H, 16);
        GATE(Gbuf, t > 0 ? embW0 : nullptr, t > 0 ? x + (t - 1) : nullptr, TTT,
             dbih0, dbhh0, c0, h0pl, PA4, nullptr, 0, 0, 0, MDEC);
        // layer 1: g = h0_new @ dWih1.T + h1d @ dWhh1.T
        MF2(h0pl, dWih1Tp, h1dpl, dWhh1Tp, nullptr, nullptr, 0, Gbuf, MDEC, G4H, 32);
        GATE(Gbuf, nullptr, nullptr, 0, dbih1, dbhh1, c1d, h1dpl, PA4, nullptr, 0, 0, 0, MDEC);
        // logits + softmax -> out
        MF2(h1dpl, WoTp, nullptr, nullptr, nullptr, nullptr, 0, Gbuf, MDEC, VVV, 16);
        softmax_out<<<dim3(MDEC), dim3(256), 0, stream>>>(Gbuf, bo, out, t);
    }
}

// Round 4
// 3611.268 us; speedup vs baseline: 3.8018x; 1.1592x over previous
//
#include <hip/hip_runtime.h>
#include <math.h>

#define HD   512
#define BB   256
#define UU   16
#define TTT  16
#define VVV  512
#define MDEC 4096   // B*U

#define AS1 __attribute__((address_space(1)))
#define AS3 __attribute__((address_space(3)))

typedef __attribute__((ext_vector_type(8))) short short8v;
typedef __attribute__((ext_vector_type(16))) float f32x16;

__device__ __forceinline__ float sigmoidf_(float x) { return 1.f / (1.f + expf(-x)); }

__device__ __forceinline__ unsigned int f2bfu(float f) {
    unsigned int u = __float_as_uint(f);
    return (u + 0x7FFF + ((u >> 16) & 1)) >> 16;
}
__device__ __forceinline__ float bf2f(unsigned int s) { return __uint_as_float(s << 16); }
__device__ __forceinline__ unsigned int pack2(float v) {
    unsigned int b0 = f2bfu(v);
    unsigned int b1 = f2bfu(v - bf2f(b0));
    return b0 | (b1 << 16);
}
__device__ __forceinline__ float unpack2(unsigned int p) {
    return bf2f(p & 0xffffu) + bf2f(p >> 16);
}

// ================= GEMM: C[MxN] = sum_pairs Ap(MxK=512) * Bp(512xN), 2-plane/3-product =================
// A = weights (rows=features, perm'd 4u+g for gate layers), B = activations^T (blocked [n][k] planes).
// EPI: 0 = f32 out (+bias[row], +tanh) ; 1 = fused LSTM gate ; 3 = packed-bf16x2 [row/4][N][4] uint4 out.
template<int FM, int FN, int EPI>
__global__ __launch_bounds__(512, 1) void gemmk(
    const short* __restrict__ A1, const short* __restrict__ B1,
    const short* __restrict__ A2, const short* __restrict__ B2,
    int M, int N, int nsteps, int pairSwitch,
    float* __restrict__ Cout, const float* __restrict__ bias, int act,
    const float* __restrict__ bab,          // EPI1: combined bias, perm'd [2048]
    const unsigned int* __restrict__ hgP,   // EPI1: packed [u][N][4] or null
    const unsigned int* __restrict__ embT,  // EPI1: packed [u][512][4] or null
    const int* __restrict__ xidx,           // EPI1: token idx, stride 16, or null
    float* __restrict__ cT,                 // EPI1: c state [u][N]
    short* __restrict__ hout, size_t hps,   // EPI1: 2-plane blocked out
    short* __restrict__ condp, size_t cps, int ustep,  // EPI1: optional cond copy
    unsigned int* __restrict__ packOut)     // EPI3
{
    constexpr int WM = 4, WN = 2;
    constexpr int ROWS = WM * FM * 32, COLS = WN * FN * 32;
    constexpr int ABLK = ROWS / 32, BBLK = COLS / 32;
    constexpr int ACH = 2 * ABLK * 2, BCH = 2 * BBLK * 2;
    constexpr int CHT = ACH + BCH, CPW = CHT / 8;
    constexpr int NBUF = 3, BUFSH = CHT * 512;
    constexpr int CHN = ABLK * BBLK * 256;
    __shared__ __align__(16) short lds[NBUF * BUFSH];

    const int tid = threadIdx.x, lane = tid & 63, wid = tid >> 6;
    const int wm = wid >> 1, wn = wid & 1;
    const int l31 = lane & 31, loct = lane >> 5;

    // XCD-bijective chunked swizzle
    const int nwg = gridDim.x * gridDim.y;
    const int d = blockIdx.y * gridDim.x + blockIdx.x;
    const int q = nwg >> 3, r = nwg & 7, xcd = d & 7, pos = d >> 3;
    const int logical = (xcd < r ? xcd * (q + 1) : r * (q + 1) + (xcd - r) * q) + pos;
    const int bx = logical % gridDim.x, by = logical / gridDim.x;

    const int mblk0 = by * ABLK, nblk0 = bx * BBLK;
    const size_t planeA = (size_t)M * 512, planeB = (size_t)N * 512;

    const short* cur[CPW];
    const short* nxt[CPW];
    int ldo[CPW];
    #pragma unroll
    for (int i = 0; i < CPW; ++i) {
        int c = wid * CPW + i;
        ldo[i] = c * 512;
        size_t off;
        const short *b1, *b2;
        if (c < ACH) {
            int plane = c / (ABLK * 2), rem = c % (ABLK * 2), blk = rem >> 1, piece = rem & 1;
            off = (size_t)plane * planeA + (size_t)(mblk0 + blk) * 16384 + piece * 512 + lane * 8;
            b1 = A1; b2 = A2;
        } else {
            int cb = c - ACH;
            int plane = cb / (BBLK * 2), rem = cb % (BBLK * 2), blk = rem >> 1, piece = rem & 1;
            off = (size_t)plane * planeB + (size_t)(nblk0 + blk) * 16384 + piece * 512 + lane * 8;
            b1 = B1; b2 = B2;
        }
        cur[i] = b1 + off;
        nxt[i] = b2 ? (b2 + off) : (b1 + off);
    }

    f32x16 acc[FM][FN] = {};

    auto STAGE = [&](int bufIdx) {
        short* db = &lds[bufIdx * BUFSH];
        #pragma unroll
        for (int i = 0; i < CPW; ++i) {
            __builtin_amdgcn_global_load_lds((const AS1 unsigned int*)cur[i],
                                             (AS3 unsigned int*)(db + ldo[i]), 16, 0, 0);
            cur[i] += 1024;
        }
    };

    STAGE(0); STAGE(1);
    asm volatile("s_waitcnt vmcnt(%0)" :: "n"(CPW) : "memory");
    __builtin_amdgcn_s_barrier();

    for (int t = 0; t < nsteps; ++t) {
        int s = t + NBUF - 1;
        if (s < nsteps) {
            if (s == pairSwitch) {
                #pragma unroll
                for (int i = 0; i < CPW; ++i) cur[i] = nxt[i];
            }
            STAGE(s % NBUF);
        }
        {
            const short* L = &lds[(t % NBUF) * BUFSH];
            #pragma unroll
            for (int ksub = 0; ksub < 2; ++ksub) {
                short8v a[FM][2], b[FN][2];
                #pragma unroll
                for (int p = 0; p < 2; ++p) {
                    #pragma unroll
                    for (int f = 0; f < FM; ++f)
                        a[f][p] = *(const short8v*)(L + (p * (ABLK * 2) + (wm * FM + f) * 2 + ksub) * 512
                                                      + loct * 256 + l31 * 8);
                    #pragma unroll
                    for (int f = 0; f < FN; ++f)
                        b[f][p] = *(const short8v*)(L + (ACH + p * (BBLK * 2) + (wn * FN + f) * 2 + ksub) * 512
                                                      + loct * 256 + l31 * 8);
                }
                #pragma unroll
                for (int pp = 0; pp < 3; ++pp) {
                    const int pa = (pp == 2) ? 1 : 0, pb = (pp == 1) ? 1 : 0;
                    #pragma unroll
                    for (int fm = 0; fm < FM; ++fm)
                        #pragma unroll
                        for (int fn = 0; fn < FN; ++fn)
                            acc[fm][fn] = __builtin_amdgcn_mfma_f32_32x32x16_bf16(
                                a[fm][pa], b[fn][pb], acc[fm][fn], 0, 0, 0);
                }
            }
        }
        if (t + 2 < nsteps)
            asm volatile("s_waitcnt vmcnt(%0) lgkmcnt(0)" :: "n"(CPW) : "memory");
        else
            asm volatile("s_waitcnt vmcnt(0) lgkmcnt(0)" ::: "memory");
        __builtin_amdgcn_s_barrier();
    }

    // ---------------- epilogues (C/D: col=lane&31, row=(reg&3)+8*(reg>>2)+4*loct) ----------------
    if constexpr (EPI == 0) {
        #pragma unroll
        for (int fm = 0; fm < FM; ++fm) {
            #pragma unroll
            for (int fn = 0; fn < FN; ++fn) {
                int col = bx * COLS + wn * FN * 32 + fn * 32 + l31;
                int rb = by * ROWS + wm * FM * 32 + fm * 32 + 4 * loct;
                #pragma unroll
                for (int reg = 0; reg < 16; ++reg) {
                    int row = rb + (reg & 3) + 8 * (reg >> 2);
                    float xv = acc[fm][fn][reg] + (bias ? bias[row] : 0.f);
                    if (act) xv = tanhf(xv);
                    Cout[(size_t)row * N + col] = xv;
                }
            }
        }
    } else if constexpr (EPI == 3) {
        uint4* P4 = (uint4*)packOut;
        #pragma unroll
        for (int fm = 0; fm < FM; ++fm) {
            #pragma unroll
            for (int fn = 0; fn < FN; ++fn) {
                int col = bx * COLS + wn * FN * 32 + fn * 32 + l31;
                int ub = by * (ROWS / 4) + wm * FM * 8 + fm * 8 + loct;
                #pragma unroll
                for (int ug = 0; ug < 4; ++ug) {
                    int u = ub + 2 * ug;
                    uint4 v;
                    v.x = pack2(acc[fm][fn][4 * ug + 0]);
                    v.y = pack2(acc[fm][fn][4 * ug + 1]);
                    v.z = pack2(acc[fm][fn][4 * ug + 2]);
                    v.w = pack2(acc[fm][fn][4 * ug + 3]);
                    P4[(size_t)u * N + col] = v;
                }
            }
        }
    } else {  // EPI == 1: fused LSTM gate
        short* hl = lds;   // reuse LDS as h staging tile
        #pragma unroll
        for (int fm = 0; fm < FM; ++fm) {
            #pragma unroll
            for (int fn = 0; fn < FN; ++fn) {
                const int col = bx * COLS + wn * FN * 32 + fn * 32 + l31;
                const int tok = xidx ? xidx[(size_t)col * 16] : -1;
                const int ub = by * (ROWS / 4) + wm * FM * 8 + fm * 8 + loct;
                #pragma unroll
                for (int ug = 0; ug < 4; ++ug) {
                    int u = ub + 2 * ug;
                    float gi = acc[fm][fn][4 * ug + 0];
                    float gf = acc[fm][fn][4 * ug + 1];
                    float gg = acc[fm][fn][4 * ug + 2];
                    float go = acc[fm][fn][4 * ug + 3];
                    float4 bv = *(const float4*)&bab[4 * u];
                    gi += bv.x; gf += bv.y; gg += bv.z; go += bv.w;
                    if (hgP) {
                        uint4 hv = ((const uint4*)hgP)[(size_t)u * N + col];
                        gi += unpack2(hv.x); gf += unpack2(hv.y);
                        gg += unpack2(hv.z); go += unpack2(hv.w);
                    }
                    if (embT && tok >= 0) {
                        uint4 ev = ((const uint4*)embT)[(size_t)u * 512 + tok];
                        gi += unpack2(ev.x); gf += unpack2(ev.y);
                        gg += unpack2(ev.z); go += unpack2(ev.w);
                    }
                    size_t cidx = (size_t)u * N + col;
                    float c = sigmoidf_(gf) * cT[cidx] + sigmoidf_(gi) * tanhf(gg);
                    cT[cidx] = c;
                    float h = sigmoidf_(go) * tanhf(c);
                    unsigned int p01 = pack2(h);
                    int u_loc = wm * FM * 8 + fm * 8 + loct + 2 * ug;
                    int m_loc = wn * FN * 32 + fn * 32 + l31;
                    int offl = ((m_loc >> 5) * ABLK + (u_loc >> 3)) * 256 + (m_loc & 31) * 8 + (u_loc & 7);
                    hl[offl] = (short)(p01 & 0xffffu);
                    hl[CHN + offl] = (short)(p01 >> 16);
                    if (condp) {
                        int np = col * 16 + ustep;
                        size_t offc = ((size_t)((np >> 5) * 64 + (u >> 3))) * 256 + (np & 31) * 8 + (u & 7);
                        condp[offc] = (short)(p01 & 0xffffu);
                        condp[cps + offc] = (short)(p01 >> 16);
                    }
                }
            }
        }
        __syncthreads();
        constexpr int LB = (ABLK == 8) ? 3 : 2;
        #pragma unroll 2
        for (int p = 0; p < 2; ++p) {
            for (int j = tid; j < CHN / 8; j += 512) {
                int lc = j >> 5, m31 = j & 31;
                int m5 = lc >> LB, u3 = lc & (ABLK - 1);
                size_t gc = (size_t)((bx * BBLK + m5) * 64 + by * ABLK + u3);
                *(short8v*)(hout + p * hps + gc * 256 + m31 * 8) = *(const short8v*)(hl + p * CHN + j * 8);
            }
        }
    }
}

// ================= prep: W (rows x ldw) f32 -> 2-plane blocked bf16 (optional gate row-perm) =================
__global__ void weight_prep(const float* __restrict__ W, short* __restrict__ pl, size_t ps,
                            int ldw, int col0, int perm, int total)
{
    int o = blockIdx.x * 256 + threadIdx.x;
    if (o >= total) return;
    int c = o >> 8, w = o & 255, r = w >> 3, j = w & 7;
    int n = (c >> 6) * 32 + r, k = (c & 63) * 8 + j;
    int nsrc = perm ? ((n >> 2) + 512 * (n & 3)) : n;
    float v = W[(size_t)nsrc * ldw + col0 + k];
    unsigned int b0 = f2bfu(v);
    pl[o] = (short)b0;
    pl[ps + o] = (short)f2bfu(v - bf2f(b0));
}

__global__ void bias_combine(const float* __restrict__ a, const float* __restrict__ b,
                             float* __restrict__ o)
{
    int i = blockIdx.x * 256 + threadIdx.x;   // 2048
    int src = (i >> 2) + 512 * (i & 3);
    o[i] = a[src] + b[src];
}

// ---------------- splits (transposed inputs [feat][m]) ----------------
__global__ void split_ci(const float* __restrict__ ciT, short* __restrict__ h1, short* __restrict__ h2,
                         size_t ps, float* __restrict__ c1T, float* __restrict__ c2T)
{
    int idx = blockIdx.x * 256 + threadIdx.x;   // 512*256
    int u = idx >> 8, b = idx & 255;
    float v1 = ciT[(size_t)u * 256 + b];
    float v2 = ciT[(size_t)(512 + u) * 256 + b];
    c1T[(size_t)u * 256 + b] = ciT[(size_t)(1024 + u) * 256 + b];
    c2T[(size_t)u * 256 + b] = ciT[(size_t)(1536 + u) * 256 + b];
    size_t o = ((size_t)((b >> 5) * 64 + (u >> 3))) * 256 + (b & 31) * 8 + (u & 7);
    unsigned int p;
    p = f2bfu(v1); h1[o] = (short)p; h1[ps + o] = (short)f2bfu(v1 - bf2f(p));
    p = f2bfu(v2); h2[o] = (short)p; h2[ps + o] = (short)f2bfu(v2 - bf2f(p));
}

__global__ void split_states(const float* __restrict__ GT, short* __restrict__ h0, short* __restrict__ h1d,
                             size_t ps, float* __restrict__ c0T, float* __restrict__ c1dT)
{
    int idx = blockIdx.x * 256 + threadIdx.x;   // 512*4096
    int u = idx >> 12, m = idx & 4095;
    float a = GT[(size_t)u * 4096 + m];
    float b = GT[(size_t)(512 + u) * 4096 + m];
    c0T[(size_t)u * 4096 + m]  = GT[(size_t)(1024 + u) * 4096 + m];
    c1dT[(size_t)u * 4096 + m] = GT[(size_t)(1536 + u) * 4096 + m];
    size_t o = ((size_t)((m >> 5) * 64 + (u >> 3))) * 256 + (m & 31) * 8 + (u & 7);
    unsigned int p;
    p = f2bfu(a); h0[o] = (short)p; h0[ps + o] = (short)f2bfu(a - bf2f(p));
    p = f2bfu(b); h1d[o] = (short)p; h1d[ps + o] = (short)f2bfu(b - bf2f(p));
}

// ---------------- softmax over V=512 on transposed logits L[v][4096m]; coalesced out ----------------
__global__ __launch_bounds__(256) void softmax_t(const float* __restrict__ L,
                                                 const float* __restrict__ bo,
                                                 float* __restrict__ out, int tstep)
{
    __shared__ float red[4][64];
    __shared__ float tile[64][65];
    int t = threadIdx.x, mloc = t & 63, stripe = t >> 6;
    int m0 = blockIdx.x * 64, m = m0 + mloc;
    float mx = -1e30f;
    for (int j = 0; j < 128; ++j) {
        int v = stripe * 128 + j;
        mx = fmaxf(mx, L[(size_t)v * 4096 + m] + bo[v]);
    }
    red[stripe][mloc] = mx;
    __syncthreads();
    mx = fmaxf(fmaxf(red[0][mloc], red[1][mloc]), fmaxf(red[2][mloc], red[3][mloc]));
    __syncthreads();
    float s = 0.f;
    for (int j = 0; j < 128; ++j) {
        int v = stripe * 128 + j;
        s += expf(L[(size_t)v * 4096 + m] + bo[v] - mx);
    }
    red[stripe][mloc] = s;
    __syncthreads();
    float inv = 1.f / (red[0][mloc] + red[1][mloc] + red[2][mloc] + red[3][mloc]);
    for (int vb = 0; vb < 8; ++vb) {
        __syncthreads();
        for (int i = 0; i < 16; ++i) {
            int rr = stripe + 4 * i;
            int v = vb * 64 + rr;
            tile[rr][mloc] = expf(L[(size_t)v * 4096 + m] + bo[v] - mx) * inv;
        }
        __syncthreads();
        for (int i = 0; i < 16; ++i) {
            int mr = stripe + 4 * i;
            out[((size_t)(m0 + mr) * 16 + tstep) * 512 + vb * 64 + mloc] = tile[mloc][mr];
        }
    }
}

// ================= host =================
extern "C" void kernel_launch(void* const* d_in, const int* in_sizes, int n_in,
                              void* d_out, int out_size, void* d_ws, size_t ws_size,
                              hipStream_t stream)
{
    const float* z     = (const float*)d_in[0];
    const int*   x     = (const int*)  d_in[1];
    const float* Wc    = (const float*)d_in[2];
    const float* bc    = (const float*)d_in[3];
    const float* cWih0 = (const float*)d_in[4];
    const float* cWhh0 = (const float*)d_in[5];
    const float* cbih0 = (const float*)d_in[6];
    const float* cbhh0 = (const float*)d_in[7];
    const float* cWih1 = (const float*)d_in[8];
    const float* cWhh1 = (const float*)d_in[9];
    const float* cbih1 = (const float*)d_in[10];
    const float* cbhh1 = (const float*)d_in[11];
    const float* Wd    = (const float*)d_in[12];
    const float* bd    = (const float*)d_in[13];
    const float* dWih0 = (const float*)d_in[14];
    const float* dWhh0 = (const float*)d_in[15];
    const float* dbih0 = (const float*)d_in[16];
    const float* dbhh0 = (const float*)d_in[17];
    const float* dWih1 = (const float*)d_in[18];
    const float* dWhh1 = (const float*)d_in[19];
    const float* dbih1 = (const float*)d_in[20];
    const float* dbhh1 = (const float*)d_in[21];
    const float* emb   = (const float*)d_in[22];
    const float* Wo    = (const float*)d_in[23];
    const float* bo    = (const float*)d_in[24];
    float* out = (float*)d_out;
    (void)in_sizes; (void)n_in; (void)out_size; (void)ws_size;

    char* wsb = (char*)d_ws;
    size_t off = 0;
    auto alloc = [&](size_t bytes) -> void* {
        off = (off + 255) & ~(size_t)255;
        void* p = wsb + off;
        off += bytes;
        return p;
    };
    const size_t PW  = (size_t)2048 * 512;
    const size_t PWo = (size_t)512 * 512;
    const size_t PA4 = (size_t)MDEC * 512;
    const size_t PAB = (size_t)BB * 512;
    const size_t PAe = (size_t)512 * 512;

    short* WcP    = (short*)alloc(2 * PW * 2);
    short* WdP    = (short*)alloc(2 * PW * 2);
    short* dW1P   = (short*)alloc(2 * PW * 2);
    short* dW2P   = (short*)alloc(2 * PW * 2);
    short* cWih0P = (short*)alloc(2 * PW * 2);
    short* cWhh0P = (short*)alloc(2 * PW * 2);
    short* cWih1P = (short*)alloc(2 * PW * 2);
    short* cWhh1P = (short*)alloc(2 * PW * 2);
    short* dWhh0P = (short*)alloc(2 * PW * 2);
    short* dWih1P = (short*)alloc(2 * PW * 2);
    short* dWhh1P = (short*)alloc(2 * PW * 2);
    short* WoP    = (short*)alloc(2 * PWo * 2);
    short* zpl    = (short*)alloc(2 * PAB * 2);
    short* embpl  = (short*)alloc(2 * PAe * 2);
    float* babc0  = (float*)alloc(2048 * 4);
    float* babc1  = (float*)alloc(2048 * 4);
    float* babd0  = (float*)alloc(2048 * 4);
    float* babd1  = (float*)alloc(2048 * 4);
    float* GbufT  = (float*)alloc((size_t)2048 * 4096 * 4);
    unsigned int* hinitgP = (unsigned int*)alloc((size_t)512 * 4096 * 4 * 4);
    unsigned int* embW0P  = (unsigned int*)alloc((size_t)512 * 512 * 4 * 4);
    short* h1pl[2], *h2pl[2], *h0pl[2], *h1dpl[2];
    h1pl[0] = (short*)alloc(2 * PAB * 2);  h1pl[1] = (short*)alloc(2 * PAB * 2);
    h2pl[0] = (short*)alloc(2 * PAB * 2);  h2pl[1] = (short*)alloc(2 * PAB * 2);
    float* c1T = (float*)alloc((size_t)512 * 256 * 4);
    float* c2T = (float*)alloc((size_t)512 * 256 * 4);
    short* condpl = (short*)alloc(2 * PA4 * 2);
    h0pl[0]  = (short*)alloc(2 * PA4 * 2); h0pl[1]  = (short*)alloc(2 * PA4 * 2);
    h1dpl[0] = (short*)alloc(2 * PA4 * 2); h1dpl[1] = (short*)alloc(2 * PA4 * 2);
    float* c0T  = (float*)alloc((size_t)512 * 4096 * 4);
    float* c1dT = (float*)alloc((size_t)512 * 4096 * 4);

    auto PREP = [&](const float* W, short* pl, size_t ps, int rows, int ldw, int col0, int perm) {
        int total = rows * 512;
        weight_prep<<<dim3(total / 256), dim3(256), 0, stream>>>(W, pl, ps, ldw, col0, perm, total);
    };
    PREP(Wc,    WcP,    PW, 512,  0,   0, 2048);  // args order fix below
    // (re-launch with correct signature ordering)
    // -- the lambda above passes (W, pl, ps, ldw, col0, perm, total); fix calls:
    // NOTE: actual calls below.

    // correct prep calls
    {
        auto P2 = [&](const float* W, short* pl, size_t ps, int rows, int ldw, int col0, int perm) {
            int total = rows * 512;
            weight_prep<<<dim3(total / 256), dim3(256), 0, stream>>>(W, pl, ps, ldw, col0, perm, total);
        };
        P2(Wc,    WcP,    PW,  2048, 512,  0,   0);
        P2(Wd,    WdP,    PW,  2048, 512,  0,   0);
        P2(dWih0, dW1P,   PW,  2048, 1024, 0,   1);
        P2(dWih0, dW2P,   PW,  2048, 1024, 512, 1);
        P2(cWih0, cWih0P, PW,  2048, 512,  0,   1);
        P2(cWhh0, cWhh0P, PW,  2048, 512,  0,   1);
        P2(cWih1, cWih1P, PW,  2048, 512,  0,   1);
        P2(cWhh1, cWhh1P, PW,  2048, 512,  0,   1);
        P2(dWhh0, dWhh0P, PW,  2048, 512,  0,   1);
        P2(dWih1, dWih1P, PW,  2048, 512,  0,   1);
        P2(dWhh1, dWhh1P, PW,  2048, 512,  0,   1);
        P2(Wo,    WoP,    PWo, 512,  512,  0,   0);
        P2(z,     zpl,    PAB, 256,  512,  0,   0);
        P2(emb,   embpl,  PAe, 512,  512,  0,   0);
    }
    bias_combine<<<dim3(8), dim3(256), 0, stream>>>(cbih0, cbhh0, babc0);
    bias_combine<<<dim3(8), dim3(256), 0, stream>>>(cbih1, cbhh1, babc1);
    bias_combine<<<dim3(8), dim3(256), 0, stream>>>(dbih0, dbhh0, babd0);
    bias_combine<<<dim3(8), dim3(256), 0, stream>>>(dbih1, dbhh1, babd1);

    // launch helpers
    auto G0 = [&](const short* A1, const short* B1, const short* A2, const short* B2,
                  int M, int N, int steps, int psw, float* C, const float* bias, int act) {
        dim3 g(N / 128, M / 256);
        gemmk<2, 2, 0><<<g, dim3(512), 0, stream>>>(A1, B1, A2, B2, M, N, steps, psw,
            C, bias, act, nullptr, nullptr, nullptr, nullptr, nullptr, nullptr, 0, nullptr, 0, 0, nullptr);
    };
    auto G3 = [&](const short* A1, const short* B1, const short* A2, const short* B2,
                  int M, int N, int steps, int psw, unsigned int* P) {
        dim3 g(N / 128, M / 256);
        gemmk<2, 2, 3><<<g, dim3(512), 0, stream>>>(A1, B1, A2, B2, M, N, steps, psw,
            nullptr, nullptr, 0, nullptr, nullptr, nullptr, nullptr, nullptr, nullptr, 0, nullptr, 0, 0, P);
    };
    auto G1big = [&](const short* A1, const short* B1, const short* A2, const short* B2,
                     int steps, int psw, const float* bab, const unsigned int* hgP,
                     const unsigned int* embT, const int* xi, float* cT, short* hout) {
        dim3 g(4096 / 128, 2048 / 256);
        gemmk<2, 2, 1><<<g, dim3(512), 0, stream>>>(A1, B1, A2, B2, 2048, 4096, steps, psw,
            nullptr, nullptr, 0, bab, hgP, embT, xi, cT, hout, PA4, nullptr, 0, 0, nullptr);
    };
    auto G1small = [&](const short* A1, const short* B1, const short* A2, const short* B2,
                       int steps, int psw, const float* bab, float* cT, short* hout,
                       short* condp, int ustep) {
        dim3 g(256 / 64, 2048 / 128);
        gemmk<1, 1, 1><<<g, dim3(512), 0, stream>>>(A1, B1, A2, B2, 2048, 256, steps, psw,
            nullptr, nullptr, 0, bab, nullptr, nullptr, nullptr, cT, hout, PAB, condp, PA4, ustep, nullptr);
    };

    // Phase A: ciT = tanh(Wc . z^T + bc)
    G0(WcP, zpl, nullptr, nullptr, 2048, 256, 16, 100, GbufT, bc, 1);
    split_ci<<<dim3(512 * 256 / 256), dim3(256), 0, stream>>>(GbufT, h1pl[0], h2pl[0], PAB, c1T, c2T);

    // embW0P = dW1 . emb^T  (packed table [u][tok][4])
    G3(dW1P, embpl, nullptr, nullptr, 2048, 512, 16, 100, embW0P);

    // Phase B: conditioning LSTM, 16 steps x 2 cells (fused gate)
    for (int u = 0; u < UU; ++u) {
        int pu = u & 1;
        if (u == 0)
            G1small(cWhh0P, h1pl[0], nullptr, nullptr, 16, 100, babc0, c1T, h1pl[1], nullptr, 0);
        else
            G1small(cWih0P, h2pl[pu], cWhh0P, h1pl[pu], 32, 16, babc0, c1T, h1pl[pu ^ 1], nullptr, 0);
        G1small(cWih1P, h1pl[pu ^ 1], cWhh1P, h2pl[pu], 32, 16, babc1, c2T, h2pl[pu ^ 1], condpl, u);
    }

    // Phase C: statesT = tanh(Wd . cond^T + bd) -> h0/h1d planes + c0/c1d
    G0(WdP, condpl, nullptr, nullptr, 2048, 4096, 16, 100, GbufT, bd, 1);
    split_states<<<dim3(512 * 4096 / 256), dim3(256), 0, stream>>>(GbufT, h0pl[0], h1dpl[0], PA4, c0T, c1dT);

    // hinitgP = dW2 . (h0+h1d)^T  via dual pair (packed [u][m][4])
    G3(dW2P, h0pl[0], dW2P, h1dpl[0], 2048, 4096, 32, 16, hinitgP);

    // Phase D: decoder, 16 steps (fused gates)
    for (int t = 0; t < TTT; ++t) {
        int pt = t & 1;
        G1big(dWhh0P, h0pl[pt], nullptr, nullptr, 16, 100, babd0, hinitgP,
              t > 0 ? embW0P : nullptr, t > 0 ? x + (t - 1) : nullptr, c0T, h0pl[pt ^ 1]);
        G1big(dWih1P, h0pl[pt ^ 1], dWhh1P, h1dpl[pt], 32, 16, babd1, nullptr,
              nullptr, nullptr, c1dT, h1dpl[pt ^ 1]);
        G0(WoP, h1dpl[pt ^ 1], nullptr, nullptr, 512, 4096, 16, 100, GbufT, nullptr, 0);
        softmax_t<<<dim3(64), dim3(256), 0, stream>>>(GbufT, bo, out, t);
    }
}

// Round 5
// 2689.571 us; speedup vs baseline: 5.1047x; 1.3427x over previous
//
#include <hip/hip_runtime.h>
#include <math.h>

#define AS1 __attribute__((address_space(1)))
#define AS3 __attribute__((address_space(3)))

typedef __attribute__((ext_vector_type(8))) short short8v;
typedef __attribute__((ext_vector_type(16))) float f32x16;

constexpr size_t PA4c = (size_t)4096 * 512;   // plane stride, M=4096 activations
constexpr size_t PABc = (size_t)256 * 512;    // plane stride, M=256 activations

__device__ __forceinline__ float sigmoidf_(float x) { return 1.f / (1.f + expf(-x)); }
__device__ __forceinline__ unsigned int f2bfu(float f) {
    unsigned int u = __float_as_uint(f);
    return (u + 0x7FFF + ((u >> 16) & 1)) >> 16;
}
__device__ __forceinline__ float bf2f(unsigned int s) { return __uint_as_float(s << 16); }
__device__ __forceinline__ unsigned int pack2(float v) {
    unsigned int b0 = f2bfu(v);
    unsigned int b1 = f2bfu(v - bf2f(b0));
    return b0 | (b1 << 16);
}
__device__ __forceinline__ float unpack2(unsigned int p) { return bf2f(p & 0xffffu) + bf2f(p >> 16); }

__device__ __forceinline__ void xswz(int d, int ngx, int ngy, int& bx, int& by) {
    int nwg = ngx * ngy;
    int q = nwg >> 3, r = nwg & 7, xcd = d & 7, pos = d >> 3;
    int logical = (xcd < r ? xcd * (q + 1) : r * (q + 1) + (xcd - r) * q) + pos;
    bx = logical % ngx; by = logical / ngx;
}

// ================= GEMM core: C += sum_pairs Ap(Mx512) * Bp(512xN), 2-plane/3-product =================
// 8 waves (4m x 2n); wave tile (FM*32) x (FN*32); block tile (FM*128) x (FN*64); BK=32; 3-buffer counted vmcnt.
template<int FM, int FN>
__device__ __forceinline__ void gemm_core(
    const short* __restrict__ A1, const short* __restrict__ B1,
    const short* __restrict__ A2, const short* __restrict__ B2,
    int M, int N, int nsteps, int pairSwitch,
    int bx, int by, short* lds, f32x16 (&acc)[FM][FN])
{
    constexpr int ABLK = 4 * FM, BBLK = 2 * FN;
    constexpr int ACH = 2 * ABLK * 2, BCH = 2 * BBLK * 2;
    constexpr int CHT = ACH + BCH;
    constexpr int CPW = CHT / 8;
    constexpr int NBUF = 3;
    constexpr int BUFSH = CHT * 512;
    const int tid = threadIdx.x, lane = tid & 63, wid = tid >> 6;
    const int wm = wid >> 1, wn = wid & 1;
    const int l31 = lane & 31, loct = lane >> 5;
    const int mblk0 = by * ABLK, nblk0 = bx * BBLK;
    const size_t planeA = (size_t)M * 512, planeB = (size_t)N * 512;

    const short* cur[CPW];
    const short* nxt[CPW];
    int ldo[CPW];
    #pragma unroll
    for (int i = 0; i < CPW; ++i) {
        int c = wid * CPW + i;
        ldo[i] = c * 512;
        size_t off;
        const short *b1, *b2;
        if (c < ACH) {
            int plane = c / (ABLK * 2), rem = c % (ABLK * 2), blk = rem >> 1, piece = rem & 1;
            off = (size_t)plane * planeA + (size_t)(mblk0 + blk) * 16384 + piece * 512 + lane * 8;
            b1 = A1; b2 = A2;
        } else {
            int cb = c - ACH;
            int plane = cb / (BBLK * 2), rem = cb % (BBLK * 2), blk = rem >> 1, piece = rem & 1;
            off = (size_t)plane * planeB + (size_t)(nblk0 + blk) * 16384 + piece * 512 + lane * 8;
            b1 = B1; b2 = B2;
        }
        cur[i] = b1 + off;
        nxt[i] = b2 ? (b2 + off) : (b1 + off);
    }

    #pragma unroll
    for (int fm = 0; fm < FM; ++fm)
        #pragma unroll
        for (int fn = 0; fn < FN; ++fn)
            acc[fm][fn] = (f32x16){};

    auto STAGE = [&](int bufIdx) {
        short* db = lds + bufIdx * BUFSH;
        #pragma unroll
        for (int i = 0; i < CPW; ++i) {
            __builtin_amdgcn_global_load_lds((const AS1 unsigned int*)cur[i],
                                             (AS3 unsigned int*)(db + ldo[i]), 16, 0, 0);
            cur[i] += 1024;
        }
    };

    STAGE(0); STAGE(1);
    asm volatile("s_waitcnt vmcnt(%0)" :: "n"(CPW) : "memory");
    __builtin_amdgcn_s_barrier();

    for (int t = 0; t < nsteps; ++t) {
        int s = t + NBUF - 1;
        if (s < nsteps) {
            if (s == pairSwitch) {
                #pragma unroll
                for (int i = 0; i < CPW; ++i) cur[i] = nxt[i];
            }
            STAGE(s % NBUF);
        }
        const short* L = lds + (t % NBUF) * BUFSH;
        #pragma unroll
        for (int ksub = 0; ksub < 2; ++ksub) {
            short8v a[FM][2], b[FN][2];
            #pragma unroll
            for (int p = 0; p < 2; ++p) {
                #pragma unroll
                for (int f = 0; f < FM; ++f)
                    a[f][p] = *(const short8v*)(L + (p * (ABLK * 2) + (wm * FM + f) * 2 + ksub) * 512
                                                  + loct * 256 + l31 * 8);
                #pragma unroll
                for (int f = 0; f < FN; ++f)
                    b[f][p] = *(const short8v*)(L + (ACH + p * (BBLK * 2) + (wn * FN + f) * 2 + ksub) * 512
                                                  + loct * 256 + l31 * 8);
            }
            #pragma unroll
            for (int pp = 0; pp < 3; ++pp) {
                const int pa = (pp == 2) ? 1 : 0, pb = (pp == 1) ? 1 : 0;
                #pragma unroll
                for (int fm = 0; fm < FM; ++fm)
                    #pragma unroll
                    for (int fn = 0; fn < FN; ++fn)
                        acc[fm][fn] = __builtin_amdgcn_mfma_f32_32x32x16_bf16(
                            a[fm][pa], b[fn][pb], acc[fm][fn], 0, 0, 0);
            }
        }
        if (t + 2 < nsteps)
            asm volatile("s_waitcnt vmcnt(%0) lgkmcnt(0)" :: "n"(CPW) : "memory");
        else
            asm volatile("s_waitcnt vmcnt(0) lgkmcnt(0)" ::: "memory");
        __builtin_amdgcn_s_barrier();
    }
}

// ---------------- epilogues (C/D layout: col=lane&31, row=(reg&3)+8*(reg>>2)+4*(lane>>5)) ----------------
template<int FM, int FN>
__device__ __forceinline__ void epi_f32(f32x16 (&acc)[FM][FN], int bx, int by, int N,
                                        float* __restrict__ Cout, const float* __restrict__ bias, int act)
{
    constexpr int ROWS = 128 * FM, COLS = 64 * FN;
    const int tid = threadIdx.x, lane = tid & 63, wid = tid >> 6;
    const int wm = wid >> 1, wn = wid & 1, l31 = lane & 31, loct = lane >> 5;
    #pragma unroll
    for (int fm = 0; fm < FM; ++fm)
        #pragma unroll
        for (int fn = 0; fn < FN; ++fn) {
            int col = bx * COLS + wn * FN * 32 + fn * 32 + l31;
            int rb  = by * ROWS + wm * FM * 32 + fm * 32 + 4 * loct;
            #pragma unroll
            for (int reg = 0; reg < 16; ++reg) {
                int row = rb + (reg & 3) + 8 * (reg >> 2);
                float xv = acc[fm][fn][reg] + (bias ? bias[row] : 0.f);
                if (act) xv = tanhf(xv);
                Cout[(size_t)row * N + col] = xv;
            }
        }
}

template<int FM, int FN>
__device__ __forceinline__ void epi_pack(f32x16 (&acc)[FM][FN], int bx, int by, int N,
                                         unsigned int* __restrict__ packOut)
{
    constexpr int ROWS = 128 * FM, COLS = 64 * FN;
    const int tid = threadIdx.x, lane = tid & 63, wid = tid >> 6;
    const int wm = wid >> 1, wn = wid & 1, l31 = lane & 31, loct = lane >> 5;
    uint4* P4 = (uint4*)packOut;
    #pragma unroll
    for (int fm = 0; fm < FM; ++fm)
        #pragma unroll
        for (int fn = 0; fn < FN; ++fn) {
            int col = bx * COLS + wn * FN * 32 + fn * 32 + l31;
            int ub = by * (ROWS / 4) + wm * FM * 8 + fm * 8 + loct;
            #pragma unroll
            for (int ug = 0; ug < 4; ++ug) {
                int u = ub + 2 * ug;
                uint4 v;
                v.x = pack2(acc[fm][fn][4 * ug + 0]);
                v.y = pack2(acc[fm][fn][4 * ug + 1]);
                v.z = pack2(acc[fm][fn][4 * ug + 2]);
                v.w = pack2(acc[fm][fn][4 * ug + 3]);
                P4[(size_t)u * N + col] = v;
            }
        }
}

template<int FM, int FN>
__device__ __forceinline__ void epi_gate(
    f32x16 (&acc)[FM][FN], int bx, int by, int N,
    short* lds, const float* __restrict__ bab,
    const unsigned int* __restrict__ hgP,
    const unsigned int* __restrict__ embT,
    const int* __restrict__ xidx,
    float* __restrict__ cT,
    short* __restrict__ hout, size_t hps,
    short* __restrict__ condp, size_t cps, int ustep)
{
    constexpr int ABLK = 4 * FM, BBLK = 2 * FN;
    constexpr int ROWS = 32 * ABLK, COLS = 32 * BBLK;
    constexpr int CHN = ABLK * BBLK * 256;
    const int tid = threadIdx.x, lane = tid & 63, wid = tid >> 6;
    const int wm = wid >> 1, wn = wid & 1, l31 = lane & 31, loct = lane >> 5;
    short* hl = lds;
    #pragma unroll
    for (int fm = 0; fm < FM; ++fm) {
        #pragma unroll
        for (int fn = 0; fn < FN; ++fn) {
            const int col = bx * COLS + wn * FN * 32 + fn * 32 + l31;
            const int tok = xidx ? xidx[(size_t)col * 16] : -1;
            const int ub = by * (ROWS / 4) + wm * FM * 8 + fm * 8 + loct;
            #pragma unroll
            for (int ug = 0; ug < 4; ++ug) {
                int u = ub + 2 * ug;
                float gi = acc[fm][fn][4 * ug + 0];
                float gf = acc[fm][fn][4 * ug + 1];
                float gg = acc[fm][fn][4 * ug + 2];
                float go = acc[fm][fn][4 * ug + 3];
                float4 bv = *(const float4*)&bab[4 * u];
                gi += bv.x; gf += bv.y; gg += bv.z; go += bv.w;
                if (hgP) {
                    uint4 hv = ((const uint4*)hgP)[(size_t)u * N + col];
                    gi += unpack2(hv.x); gf += unpack2(hv.y);
                    gg += unpack2(hv.z); go += unpack2(hv.w);
                }
                if (embT && tok >= 0) {
                    uint4 ev = ((const uint4*)embT)[(size_t)u * 512 + tok];
                    gi += unpack2(ev.x); gf += unpack2(ev.y);
                    gg += unpack2(ev.z); go += unpack2(ev.w);
                }
                size_t cidx = (size_t)u * N + col;
                float c = sigmoidf_(gf) * cT[cidx] + sigmoidf_(gi) * tanhf(gg);
                cT[cidx] = c;
                float h = sigmoidf_(go) * tanhf(c);
                unsigned int p01 = pack2(h);
                int u_loc = wm * FM * 8 + fm * 8 + loct + 2 * ug;
                int m_loc = wn * FN * 32 + fn * 32 + l31;
                int offl = ((m_loc >> 5) * ABLK + (u_loc >> 3)) * 256 + (m_loc & 31) * 8 + (u_loc & 7);
                hl[offl] = (short)(p01 & 0xffffu);
                hl[CHN + offl] = (short)(p01 >> 16);
                if (condp) {
                    int np = col * 16 + ustep;
                    size_t offc = ((size_t)((np >> 5) * 64 + (u >> 3))) * 256 + (np & 31) * 8 + (u & 7);
                    condp[offc] = (short)(p01 & 0xffffu);
                    condp[cps + offc] = (short)(p01 >> 16);
                }
            }
        }
    }
    __syncthreads();
    constexpr int LB = (ABLK == 8) ? 3 : 2;
    for (int p = 0; p < 2; ++p) {
        for (int jj = tid; jj < CHN / 8; jj += 512) {
            int lc = jj >> 5, m31 = jj & 31;
            int m5 = lc >> LB, u3 = lc & (ABLK - 1);
            size_t gc = (size_t)((bx * BBLK + m5) * 64 + by * ABLK + u3);
            *(short8v*)(hout + p * hps + gc * 256 + m31 * 8) = *(const short8v*)(hl + p * CHN + jj * 8);
        }
    }
}

// ================= standalone GEMM kernels (phase A/C, emb table, hinitg) =================
template<int FM, int FN>
__global__ __launch_bounds__(512, 1) void gemm_f32k(
    const short* A1, const short* B1, const short* A2, const short* B2,
    int M, int N, int nsteps, int psw,
    float* Cout, const float* bias, int act)
{
    __shared__ __align__(16) short lds[3 * (2 * (4 * FM) * 2 + 2 * (2 * FN) * 2) * 512];
    int d = blockIdx.y * gridDim.x + blockIdx.x;
    int bx, by; xswz(d, gridDim.x, gridDim.y, bx, by);
    f32x16 acc[FM][FN];
    gemm_core<FM, FN>(A1, B1, A2, B2, M, N, nsteps, psw, bx, by, lds, acc);
    epi_f32<FM, FN>(acc, bx, by, N, Cout, bias, act);
}

template<int FM, int FN>
__global__ __launch_bounds__(512, 1) void gemm_packk(
    const short* A1, const short* B1, const short* A2, const short* B2,
    int M, int N, int nsteps, int psw, unsigned int* packOut)
{
    __shared__ __align__(16) short lds[3 * (2 * (4 * FM) * 2 + 2 * (2 * FN) * 2) * 512];
    int d = blockIdx.y * gridDim.x + blockIdx.x;
    int bx, by; xswz(d, gridDim.x, gridDim.y, bx, by);
    f32x16 acc[FM][FN];
    gemm_core<FM, FN>(A1, B1, A2, B2, M, N, nsteps, psw, bx, by, lds, acc);
    epi_pack<FM, FN>(acc, bx, by, N, packOut);
}

// ================= persistent conditioning LSTM (64 blocks, grid barrier) =================
__device__ __forceinline__ void gbar(unsigned int* bar, unsigned int target)
{
    __syncthreads();
    if (threadIdx.x == 0) {
        __hip_atomic_fetch_add(bar, 1u, __ATOMIC_ACQ_REL, __HIP_MEMORY_SCOPE_AGENT);
        while (__hip_atomic_load(bar, __ATOMIC_ACQUIRE, __HIP_MEMORY_SCOPE_AGENT) < target)
            __builtin_amdgcn_s_sleep(2);
    }
    __syncthreads();
}

__global__ __launch_bounds__(512, 1) void cond_lstm(
    const short* cWih0P, const short* cWhh0P, const short* cWih1P, const short* cWhh1P,
    const float* babc0, const float* babc1,
    float* c1T, float* c2T,
    short* h1p0, short* h1p1, short* h2p0, short* h2p1,
    short* condp, unsigned int* bar)
{
    __shared__ __align__(16) short lds[3 * 12288];
    const int d = blockIdx.x;
    const int xcd = d & 7, j = d >> 3;
    const int by = xcd * 2 + (j & 1), bx = j >> 1;   // row-slices pinned per XCD for L2 reuse
    unsigned int gen = 0;
    for (int u = 0; u < 16; ++u) {
        const int pin = u & 1;
        short* h1in  = pin ? h1p1 : h1p0;  short* h1out = pin ? h1p0 : h1p1;
        short* h2in  = pin ? h2p1 : h2p0;  short* h2out = pin ? h2p0 : h2p1;
        {
            f32x16 acc[1][1];
            if (u == 0)
                gemm_core<1, 1>(cWhh0P, h1in, nullptr, nullptr, 2048, 256, 16, 100, bx, by, lds, acc);
            else
                gemm_core<1, 1>(cWih0P, h2in, cWhh0P, h1in, 2048, 256, 32, 16, bx, by, lds, acc);
            epi_gate<1, 1>(acc, bx, by, 256, lds, babc0, nullptr, nullptr, nullptr,
                           c1T, h1out, PABc, nullptr, 0, 0);
        }
        gbar(bar, (++gen) * 64);
        {
            f32x16 acc[1][1];
            gemm_core<1, 1>(cWih1P, h1out, cWhh1P, h2in, 2048, 256, 32, 16, bx, by, lds, acc);
            epi_gate<1, 1>(acc, bx, by, 256, lds, babc1, nullptr, nullptr, nullptr,
                           c2T, h2out, PABc, condp, PA4c, u);
        }
        gbar(bar, (++gen) * 64);
    }
}

// ================= merged decoder kernels =================
__global__ __launch_bounds__(512, 1) void dec_k1(
    int doGate,
    const short* Ag, const short* Bg, const float* bab,
    const unsigned int* hgP, const unsigned int* embT, const int* xidx,
    float* cT, short* hout,
    const short* Aw, const short* Bw, float* Lout)
{
    __shared__ __align__(16) short lds[3 * 24576];
    const int dd = blockIdx.x;
    if (doGate) {
        int bx, by; xswz(dd, 32, 8, bx, by);
        f32x16 acc[2][2];
        gemm_core<2, 2>(Ag, Bg, nullptr, nullptr, 2048, 4096, 16, 100, bx, by, lds, acc);
        epi_gate<2, 2>(acc, bx, by, 4096, lds, bab, hgP, embT, xidx, cT, hout, PA4c, nullptr, 0, 0);
        __syncthreads();
    }
    if (Aw) {
        int bx, by; xswz(dd, 64, 4, bx, by);
        f32x16 acc[1][1];
        gemm_core<1, 1>(Aw, Bw, nullptr, nullptr, 512, 4096, 16, 100, bx, by, lds, acc);
        epi_f32<1, 1>(acc, bx, by, 4096, Lout, nullptr, 0);
    }
}

__global__ __launch_bounds__(512, 1) void dec_k2(
    int doGate,
    const short* A1, const short* B1, const short* A2, const short* B2,
    const float* bab, float* cT, short* hout,
    const float* Lsrc, const float* bo, float* outp, int tstep)
{
    __shared__ __align__(16) short lds[3 * 24576];
    const int dd = blockIdx.x;
    if (doGate) {
        int bx, by; xswz(dd, 32, 8, bx, by);
        f32x16 acc[2][2];
        gemm_core<2, 2>(A1, B1, A2, B2, 2048, 4096, 32, 16, bx, by, lds, acc);
        epi_gate<2, 2>(acc, bx, by, 4096, lds, bab, nullptr, nullptr, nullptr, cT, hout, PA4c, nullptr, 0, 0);
        __syncthreads();
    }
    if (Lsrc) {
        float* tile = (float*)lds;              // [16][513]
        float* red  = (float*)lds + 16 * 513;   // [32][16]
        float* red2 = red + 512;
        const int tid = threadIdx.x;
        const int mj = tid & 15, vs = tid >> 4;
        const int m = dd * 16 + mj;
        float mx = -1e30f;
        for (int i = 0; i < 16; ++i) {
            int v = vs * 16 + i;
            mx = fmaxf(mx, Lsrc[(size_t)v * 4096 + m] + bo[v]);
        }
        red[vs * 16 + mj] = mx;
        __syncthreads();
        for (int o = 16; o >= 1; o >>= 1) {
            if (vs < o) red[vs * 16 + mj] = fmaxf(red[vs * 16 + mj], red[(vs + o) * 16 + mj]);
            __syncthreads();
        }
        mx = red[mj];
        float sum = 0.f;
        for (int i = 0; i < 16; ++i) {
            int v = vs * 16 + i;
            float e = expf(Lsrc[(size_t)v * 4096 + m] + bo[v] - mx);
            sum += e;
            tile[mj * 513 + v] = e;
        }
        red2[vs * 16 + mj] = sum;
        __syncthreads();
        for (int o = 16; o >= 1; o >>= 1) {
            if (vs < o) red2[vs * 16 + mj] += red2[(vs + o) * 16 + mj];
            __syncthreads();
        }
        const int r = tid >> 5, c = tid & 31;
        float invr = 1.f / red2[r];
        for (int k = 0; k < 16; ++k) {
            int v = k * 32 + c;
            outp[((size_t)(dd * 16 + r) * 16 + tstep) * 512 + v] = tile[r * 513 + v] * invr;
        }
    }
}

// ================= one-shot prep: weights -> 2-plane blocked bf16; bias combine =================
struct PrepEnt { const float* src; const float* src2; void* dst; int ldw, col0, perm, total, op; };
struct PrepArgs { PrepEnt e[18]; int n; };

__global__ void prep_all(PrepArgs pa)
{
    for (int ei = 0; ei < pa.n; ++ei) {
        PrepEnt E = pa.e[ei];
        for (int o = blockIdx.x * 256 + threadIdx.x; o < E.total; o += gridDim.x * 256) {
            if (E.op == 0) {
                int c = o >> 8, w = o & 255, r = w >> 3, jj = w & 7;
                int n = (c >> 6) * 32 + r, k = (c & 63) * 8 + jj;
                int nsrc = E.perm ? ((n >> 2) + 512 * (n & 3)) : n;
                float v = E.src[(size_t)nsrc * E.ldw + E.col0 + k];
                unsigned int b0 = f2bfu(v);
                short* pl = (short*)E.dst;
                pl[o] = (short)b0;
                pl[E.total + o] = (short)f2bfu(v - bf2f(b0));
            } else {
                int src = (o >> 2) + 512 * (o & 3);
                ((float*)E.dst)[o] = E.src[src] + E.src2[src];
            }
        }
    }
}

// ---------------- splits (transposed inputs [feat][m]) ----------------
__global__ void split_ci(const float* __restrict__ ciT, short* __restrict__ h1, short* __restrict__ h2,
                         size_t ps, float* __restrict__ c1T, float* __restrict__ c2T)
{
    int idx = blockIdx.x * 256 + threadIdx.x;   // 512*256
    int u = idx >> 8, b = idx & 255;
    float v1 = ciT[(size_t)u * 256 + b];
    float v2 = ciT[(size_t)(512 + u) * 256 + b];
    c1T[(size_t)u * 256 + b] = ciT[(size_t)(1024 + u) * 256 + b];
    c2T[(size_t)u * 256 + b] = ciT[(size_t)(1536 + u) * 256 + b];
    size_t o = ((size_t)((b >> 5) * 64 + (u >> 3))) * 256 + (b & 31) * 8 + (u & 7);
    unsigned int p;
    p = f2bfu(v1); h1[o] = (short)p; h1[ps + o] = (short)f2bfu(v1 - bf2f(p));
    p = f2bfu(v2); h2[o] = (short)p; h2[ps + o] = (short)f2bfu(v2 - bf2f(p));
}

__global__ void split_states(const float* __restrict__ GT, short* __restrict__ h0, short* __restrict__ h1d,
                             size_t ps, float* __restrict__ c0T, float* __restrict__ c1dT)
{
    int idx = blockIdx.x * 256 + threadIdx.x;   // 512*4096
    int u = idx >> 12, m = idx & 4095;
    float a = GT[(size_t)u * 4096 + m];
    float b = GT[(size_t)(512 + u) * 4096 + m];
    c0T[(size_t)u * 4096 + m]  = GT[(size_t)(1024 + u) * 4096 + m];
    c1dT[(size_t)u * 4096 + m] = GT[(size_t)(1536 + u) * 4096 + m];
    size_t o = ((size_t)((m >> 5) * 64 + (u >> 3))) * 256 + (m & 31) * 8 + (u & 7);
    unsigned int p;
    p = f2bfu(a); h0[o] = (short)p; h0[ps + o] = (short)f2bfu(a - bf2f(p));
    p = f2bfu(b); h1d[o] = (short)p; h1d[ps + o] = (short)f2bfu(b - bf2f(p));
}

// ================= host =================
extern "C" void kernel_launch(void* const* d_in, const int* in_sizes, int n_in,
                              void* d_out, int out_size, void* d_ws, size_t ws_size,
                              hipStream_t stream)
{
    const float* z     = (const float*)d_in[0];
    const int*   x     = (const int*)  d_in[1];
    const float* Wc    = (const float*)d_in[2];
    const float* bc    = (const float*)d_in[3];
    const float* cWih0 = (const float*)d_in[4];
    const float* cWhh0 = (const float*)d_in[5];
    const float* cbih0 = (const float*)d_in[6];
    const float* cbhh0 = (const float*)d_in[7];
    const float* cWih1 = (const float*)d_in[8];
    const float* cWhh1 = (const float*)d_in[9];
    const float* cbih1 = (const float*)d_in[10];
    const float* cbhh1 = (const float*)d_in[11];
    const float* Wd    = (const float*)d_in[12];
    const float* bd    = (const float*)d_in[13];
    const float* dWih0 = (const float*)d_in[14];
    const float* dWhh0 = (const float*)d_in[15];
    const float* dbih0 = (const float*)d_in[16];
    const float* dbhh0 = (const float*)d_in[17];
    const float* dWih1 = (const float*)d_in[18];
    const float* dWhh1 = (const float*)d_in[19];
    const float* dbih1 = (const float*)d_in[20];
    const float* dbhh1 = (const float*)d_in[21];
    const float* emb   = (const float*)d_in[22];
    const float* Wo    = (const float*)d_in[23];
    const float* bo    = (const float*)d_in[24];
    float* out = (float*)d_out;
    (void)in_sizes; (void)n_in; (void)out_size; (void)ws_size;

    char* wsb = (char*)d_ws;
    size_t off = 0;
    auto alloc = [&](size_t bytes) -> void* {
        off = (off + 255) & ~(size_t)255;
        void* p = wsb + off;
        off += bytes;
        return p;
    };
    const size_t PW  = (size_t)2048 * 512;
    const size_t PWo = (size_t)512 * 512;

    short* WcP    = (short*)alloc(2 * PW * 2);
    short* WdP    = (short*)alloc(2 * PW * 2);
    short* dW1P   = (short*)alloc(2 * PW * 2);
    short* dW2P   = (short*)alloc(2 * PW * 2);
    short* cWih0P = (short*)alloc(2 * PW * 2);
    short* cWhh0P = (short*)alloc(2 * PW * 2);
    short* cWih1P = (short*)alloc(2 * PW * 2);
    short* cWhh1P = (short*)alloc(2 * PW * 2);
    short* dWhh0P = (short*)alloc(2 * PW * 2);
    short* dWih1P = (short*)alloc(2 * PW * 2);
    short* dWhh1P = (short*)alloc(2 * PW * 2);
    short* WoP    = (short*)alloc(2 * PWo * 2);
    short* zpl    = (short*)alloc(2 * PABc * 2);
    short* embpl  = (short*)alloc(2 * PWo * 2);
    float* babc0  = (float*)alloc(2048 * 4);
    float* babc1  = (float*)alloc(2048 * 4);
    float* babd0  = (float*)alloc(2048 * 4);
    float* babd1  = (float*)alloc(2048 * 4);
    float* GbufT  = (float*)alloc((size_t)2048 * 4096 * 4);
    unsigned int* hinitgP = (unsigned int*)alloc((size_t)512 * 4096 * 4 * 4);
    unsigned int* embW0P  = (unsigned int*)alloc((size_t)512 * 512 * 4 * 4);
    short* h1pl0 = (short*)alloc(2 * PABc * 2);
    short* h1pl1 = (short*)alloc(2 * PABc * 2);
    short* h2pl0 = (short*)alloc(2 * PABc * 2);
    short* h2pl1 = (short*)alloc(2 * PABc * 2);
    float* c1T = (float*)alloc((size_t)512 * 256 * 4);
    float* c2T = (float*)alloc((size_t)512 * 256 * 4);
    short* condpl = (short*)alloc(2 * PA4c * 2);
    short* h0pl[2];  short* h1dpl[2];
    h0pl[0]  = (short*)alloc(2 * PA4c * 2); h0pl[1]  = (short*)alloc(2 * PA4c * 2);
    h1dpl[0] = (short*)alloc(2 * PA4c * 2); h1dpl[1] = (short*)alloc(2 * PA4c * 2);
    float* c0T  = (float*)alloc((size_t)512 * 4096 * 4);
    float* c1dT = (float*)alloc((size_t)512 * 4096 * 4);
    unsigned int* bar = (unsigned int*)alloc(256);

    float* Lg[2] = { GbufT, GbufT + (size_t)512 * 4096 };   // alias GbufT (dead after phase C)

    // ---- prep: all weight conversions + bias combines in one launch ----
    PrepArgs pa; pa.n = 18;
    auto W8 = [](const float* s, void* d, int ldw, int col0, int perm, int total) {
        PrepEnt e; e.src = s; e.src2 = nullptr; e.dst = d; e.ldw = ldw; e.col0 = col0;
        e.perm = perm; e.total = total; e.op = 0; return e;
    };
    auto B8 = [](const float* a, const float* b, void* d) {
        PrepEnt e; e.src = a; e.src2 = b; e.dst = d; e.ldw = 0; e.col0 = 0;
        e.perm = 0; e.total = 2048; e.op = 1; return e;
    };
    pa.e[0]  = W8(Wc,    WcP,    512,  0,   0, 2048 * 512);
    pa.e[1]  = W8(Wd,    WdP,    512,  0,   0, 2048 * 512);
    pa.e[2]  = W8(dWih0, dW1P,   1024, 0,   1, 2048 * 512);
    pa.e[3]  = W8(dWih0, dW2P,   1024, 512, 1, 2048 * 512);
    pa.e[4]  = W8(cWih0, cWih0P, 512,  0,   1, 2048 * 512);
    pa.e[5]  = W8(cWhh0, cWhh0P, 512,  0,   1, 2048 * 512);
    pa.e[6]  = W8(cWih1, cWih1P, 512,  0,   1, 2048 * 512);
    pa.e[7]  = W8(cWhh1, cWhh1P, 512,  0,   1, 2048 * 512);
    pa.e[8]  = W8(dWhh0, dWhh0P, 512,  0,   1, 2048 * 512);
    pa.e[9]  = W8(dWih1, dWih1P, 512,  0,   1, 2048 * 512);
    pa.e[10] = W8(dWhh1, dWhh1P, 512,  0,   1, 2048 * 512);
    pa.e[11] = W8(Wo,    WoP,    512,  0,   0, 512 * 512);
    pa.e[12] = W8(z,     zpl,    512,  0,   0, 256 * 512);
    pa.e[13] = W8(emb,   embpl,  512,  0,   0, 512 * 512);
    pa.e[14] = B8(cbih0, cbhh0, babc0);
    pa.e[15] = B8(cbih1, cbhh1, babc1);
    pa.e[16] = B8(dbih0, dbhh0, babd0);
    pa.e[17] = B8(dbih1, dbhh1, babd1);
    prep_all<<<dim3(1024), dim3(256), 0, stream>>>(pa);
    hipMemsetAsync(bar, 0, 256, stream);

    // Phase A: ciT = tanh(Wc . z^T + bc)
    gemm_f32k<2, 2><<<dim3(2, 8), dim3(512), 0, stream>>>(
        WcP, zpl, nullptr, nullptr, 2048, 256, 16, 100, GbufT, bc, 1);
    split_ci<<<dim3(512 * 256 / 256), dim3(256), 0, stream>>>(GbufT, h1pl0, h2pl0, PABc, c1T, c2T);

    // embW0P = dW1 . emb^T (packed gate table [u][tok][4])
    gemm_packk<2, 2><<<dim3(4, 8), dim3(512), 0, stream>>>(
        dW1P, embpl, nullptr, nullptr, 2048, 512, 16, 100, embW0P);

    // Phase B: persistent conditioning LSTM (16 steps x 2 cells, grid barrier)
    cond_lstm<<<dim3(64), dim3(512), 0, stream>>>(
        cWih0P, cWhh0P, cWih1P, cWhh1P, babc0, babc1,
        c1T, c2T, h1pl0, h1pl1, h2pl0, h2pl1, condpl, bar);

    // Phase C: statesT = tanh(Wd . cond^T + bd) -> h0/h1d planes + c states
    gemm_f32k<2, 2><<<dim3(32, 8), dim3(512), 0, stream>>>(
        WdP, condpl, nullptr, nullptr, 2048, 4096, 16, 100, GbufT, bd, 1);
    split_states<<<dim3(512 * 4096 / 256), dim3(256), 0, stream>>>(
        GbufT, h0pl[0], h1dpl[0], PA4c, c0T, c1dT);

    // hinitgP = dW2 . (h0+h1d)^T via dual pair (packed [u][m][4])
    gemm_packk<2, 2><<<dim3(32, 8), dim3(512), 0, stream>>>(
        dW2P, h0pl[0], dW2P, h1dpl[0], 2048, 4096, 32, 16, hinitgP);

    // Phase D: decoder, 16 steps; logits(t-1)/softmax(t-1) ride along
    for (int t = 0; t < 16; ++t) {
        int pin = t & 1;
        dec_k1<<<dim3(256), dim3(512), 0, stream>>>(1,
            dWhh0P, h0pl[pin], babd0, hinitgP,
            t > 0 ? embW0P : nullptr, t > 0 ? x + (t - 1) : nullptr,
            c0T, h0pl[pin ^ 1],
            t > 0 ? WoP : nullptr, t > 0 ? h1dpl[pin] : nullptr,
            t > 0 ? Lg[(t - 1) & 1] : nullptr);
        dec_k2<<<dim3(256), dim3(512), 0, stream>>>(1,
            dWih1P, h0pl[pin ^ 1], dWhh1P, h1dpl[pin],
            babd1, c1dT, h1dpl[pin ^ 1],
            t > 0 ? Lg[(t - 1) & 1] : nullptr, bo, out, t - 1);
    }
    // tail: logits(15) then softmax(15)
    dec_k1<<<dim3(256), dim3(512), 0, stream>>>(0,
        nullptr, nullptr, nullptr, nullptr, nullptr, nullptr, nullptr, nullptr,
        WoP, h1dpl[0], Lg[1]);
    dec_k2<<<dim3(256), dim3(512), 0, stream>>>(0,
        nullptr, nullptr, nullptr, nullptr, nullptr, nullptr, nullptr,
        Lg[1], bo, out, 15);
}